// Round 1
// baseline (292.207 us; speedup 1.0000x reference)
//
#include <hip/hip_runtime.h>
#include <hip/hip_bf16.h>
#include <math.h>

typedef unsigned short u16;
typedef short bf16x8 __attribute__((ext_vector_type(8)));
typedef float f32x4 __attribute__((ext_vector_type(4)));

__device__ __forceinline__ u16 f2b(float f) {
    __hip_bfloat16 h = __float2bfloat16(f);
    return *reinterpret_cast<u16*>(&h);
}
__device__ __forceinline__ float b2f(u16 v) {
    __hip_bfloat16 h;
    *reinterpret_cast<u16*>(&h) = v;
    return __bfloat162float(h);
}

// ---------------- cast / transpose kernels ----------------

// cat = concat([h, x], axis=1) -> bf16 [b*512][1024]
__global__ __launch_bounds__(256) void cast_cat(const float* __restrict__ x,
                                                const float* __restrict__ h,
                                                u16* __restrict__ catBF) {
    int idx = blockIdx.x * 256 + threadIdx.x;      // < 4096*1024
    int c = idx & 1023, r = idx >> 10;
    int b = r >> 9, pos = r & 511;
    float v = (pos < 256) ? h[(b * 256 + pos) * 1024 + c]
                          : x[(b * 256 + pos - 256) * 1024 + c];
    catBF[idx] = f2b(v);
}

__global__ __launch_bounds__(256) void cast_bf16(const float* __restrict__ in,
                                                 u16* __restrict__ out) {
    int idx = blockIdx.x * 256 + threadIdx.x;
    out[idx] = f2b(in[idx]);
}

// W [K][N] f32 -> WT [N][K] bf16
__global__ __launch_bounds__(256) void transpose_cast(const float* __restrict__ W,
                                                      u16* __restrict__ WT,
                                                      int K, int N) {
    __shared__ float tile[32][33];
    int nb = blockIdx.x * 32, kb = blockIdx.y * 32;
    int tx = threadIdx.x & 31, ty = threadIdx.x >> 5;  // ty 0..7
    #pragma unroll
    for (int i = 0; i < 32; i += 8)
        tile[ty + i][tx] = W[(long)(kb + ty + i) * N + nb + tx];
    __syncthreads();
    #pragma unroll
    for (int i = 0; i < 32; i += 8)
        WT[(long)(nb + ty + i) * K + kb + tx] = f2b(tile[tx][ty + i]);
}

// CK[b][h][j] = sum_d u[d] * K[b][h][j][d]
__global__ __launch_bounds__(256) void ck_kernel(const u16* __restrict__ Kt,
                                                 const float* __restrict__ u,
                                                 float* __restrict__ CK) {
    int idx = blockIdx.x * 256 + threadIdx.x;  // < 8*16*512
    const u16* kp = Kt + (long)idx * 64;
    float s = 0.f;
    #pragma unroll
    for (int d = 0; d < 64; ++d) s += u[d] * b2f(kp[d]);
    CK[idx] = s;
}

// VR[h][s] = sum_d v[d] * RW[s][h*64+d]
__global__ __launch_bounds__(256) void vr_kernel(const u16* __restrict__ RW,
                                                 const float* __restrict__ v,
                                                 float* __restrict__ VR) {
    int idx = blockIdx.x * 256 + threadIdx.x;  // < 16*1024
    int h = idx >> 10, s = idx & 1023;
    const u16* rp = RW + (long)s * 1024 + h * 64;
    float acc = 0.f;
    #pragma unroll
    for (int d = 0; d < 64; ++d) acc += v[d] * b2f(rp[d]);
    VR[idx] = acc;
}

// ---------------- generic C = A @ B^T GEMM (bf16 in, fp32 acc) ----------------
// A: [M][K] bf16 row-major (lda), B: [N][K] bf16 row-major (ldb).
// 64x64 tile, BK=32, 256 threads = 4 waves in 2x2 arrangement.

struct EpiQKV {  // scatter qkv into Q [h][b][i][d], K [b][h][t][d], V^T [b][h][d][t]
    u16 *Q, *Kt, *VT;
    __device__ void operator()(int z, int row, int col, float val) const {
        int b = row >> 9, pos = row & 511;
        int sec = col >> 10, cc = col & 1023;
        int head = cc >> 6, d = cc & 63;
        u16 bv = f2b(val);
        if (sec == 0) {
            if (pos >= 256)
                Q[(long)((head * 8 + b) * 256 + (pos - 256)) * 64 + d] = bv;
        } else if (sec == 1) {
            Kt[(long)((b * 16 + head) * 512 + pos) * 64 + d] = bv;
        } else {
            VT[(long)((b * 16 + head) * 64 + d) * 512 + pos] = bv;
        }
    }
};

struct EpiStoreBf {
    u16* C; long ldc; long strideZ;
    __device__ void operator()(int z, int row, int col, float val) const {
        C[(long)z * strideZ + (long)row * ldc + col] = f2b(val);
    }
};

struct EpiStoreF32 {
    float* C; long ldc;
    __device__ void operator()(int z, int row, int col, float val) const {
        C[(long)row * ldc + col] = val;
    }
};

template <typename Epi>
__global__ __launch_bounds__(256) void gemm_bt(const u16* __restrict__ A, int lda, long strideAz,
                                               const u16* __restrict__ B, int ldb, long strideBz,
                                               int K, Epi epi) {
    constexpr int LDT = 56;  // 112 B row stride: 16B-aligned, <=2-way bank alias (free)
    __shared__ alignas(16) u16 As[64 * LDT];
    __shared__ alignas(16) u16 Bs[64 * LDT];
    int n0 = blockIdx.x * 64, m0 = blockIdx.y * 64, z = blockIdx.z;
    const u16* Ab = A + (long)z * strideAz + (long)m0 * lda;
    const u16* Bb = B + (long)z * strideBz + (long)n0 * ldb;
    int tid = threadIdx.x;
    int wave = tid >> 6, lane = tid & 63;
    int wm = wave >> 1, wn = wave & 1;
    int lrow = lane & 15, lquad = lane >> 4;
    int srow = tid >> 2, scol = (tid & 3) * 8;  // staging: 64 rows x 32 cols, 16B/thread
    f32x4 acc[2][2] = {};
    for (int k0 = 0; k0 < K; k0 += 32) {
        *(bf16x8*)(As + srow * LDT + scol) = *(const bf16x8*)(Ab + (long)srow * lda + k0 + scol);
        *(bf16x8*)(Bs + srow * LDT + scol) = *(const bf16x8*)(Bb + (long)srow * ldb + k0 + scol);
        __syncthreads();
        bf16x8 af[2], bf[2];
        #pragma unroll
        for (int mt = 0; mt < 2; ++mt)
            af[mt] = *(const bf16x8*)(As + (wm * 32 + mt * 16 + lrow) * LDT + lquad * 8);
        #pragma unroll
        for (int nt = 0; nt < 2; ++nt)
            bf[nt] = *(const bf16x8*)(Bs + (wn * 32 + nt * 16 + lrow) * LDT + lquad * 8);
        #pragma unroll
        for (int mt = 0; mt < 2; ++mt)
            #pragma unroll
            for (int nt = 0; nt < 2; ++nt)
                acc[mt][nt] = __builtin_amdgcn_mfma_f32_16x16x32_bf16(af[mt], bf[nt], acc[mt][nt], 0, 0, 0);
        __syncthreads();
    }
    #pragma unroll
    for (int mt = 0; mt < 2; ++mt)
        #pragma unroll
        for (int nt = 0; nt < 2; ++nt)
            #pragma unroll
            for (int r = 0; r < 4; ++r) {
                int row = m0 + wm * 32 + mt * 16 + lquad * 4 + r;
                int col = n0 + wn * 32 + nt * 16 + lrow;
                epi(z, row, col, acc[mt][nt][r]);
            }
}

// ---------------- fused attention ----------------
// grid: (i-tile=16, h=16, b=8), 256 threads = 4 waves.
// scores S[16][512] in LDS fp32; softmax; PV via MFMA from LDS bf16 probs.
__global__ __launch_bounds__(256) void attn_kernel(const u16* __restrict__ Qbf,
                                                   const u16* __restrict__ Kt,
                                                   const u16* __restrict__ VT,
                                                   const u16* __restrict__ QR,
                                                   const float* __restrict__ CK,
                                                   const float* __restrict__ VR,
                                                   u16* __restrict__ attnOut) {
    constexpr int SLDF = 516;  // float stride (x4B), float4-aligned
    constexpr int SLDB = 520;  // u16 stride = 1040 B, 16B-multiple, 2-way alias only
    __shared__ alignas(16) float S[16 * SLDF];
    __shared__ alignas(16) u16 Sb[16 * SLDB];
    __shared__ float rowinv[16];
    int i0 = blockIdx.x * 16;
    int h = blockIdx.y, b = blockIdx.z;
    int tid = threadIdx.x, wave = tid >> 6, lane = tid & 63;
    int lrow = lane & 15, lquad = lane >> 4;

    // Q fragments (A operand), shared by all j-tiles
    const u16* qbase = Qbf + (long)((h * 8 + b) * 256 + i0 + lrow) * 64;
    bf16x8 aq0 = *(const bf16x8*)(qbase + lquad * 8);
    bf16x8 aq1 = *(const bf16x8*)(qbase + 32 + lquad * 8);

    const u16* kbase = Kt + (long)((b * 16 + h) * 512) * 64;
    const float* ckbase = CK + (b * 16 + h) * 512;
    const u16* qrbase = QR + (long)((h * 8 + b) * 256) * 1024;
    const float* vrbase = VR + h * 1024;

    // ---- scores: wave w covers j in [w*128, w*128+128) ----
    for (int jt = 0; jt < 8; ++jt) {
        int j0 = wave * 128 + jt * 16;
        const u16* kp = kbase + (long)(j0 + lrow) * 64;
        bf16x8 bk0 = *(const bf16x8*)(kp + lquad * 8);
        bf16x8 bk1 = *(const bf16x8*)(kp + 32 + lquad * 8);
        f32x4 acc = {0.f, 0.f, 0.f, 0.f};
        acc = __builtin_amdgcn_mfma_f32_16x16x32_bf16(aq0, bk0, acc, 0, 0, 0);
        acc = __builtin_amdgcn_mfma_f32_16x16x32_bf16(aq1, bk1, acc, 0, 0, 0);
        int j = j0 + lrow;
        float ck = ckbase[j];
        #pragma unroll
        for (int r = 0; r < 4; ++r) {
            int iloc = lquad * 4 + r;
            int i = i0 + iloc;
            int s = (j - i - 256) & 1023;
            float val = acc[r] + ck + b2f(qrbase[(long)i * 1024 + s]) + vrbase[s];
            bool ok = (j >= 256) ? ((j - 256) <= i) : (j >= i);
            S[iloc * SLDF + j] = ok ? val * 0.125f : -1e30f;
        }
    }
    __syncthreads();

    // ---- softmax: 16 threads per row, 32 elems each ----
    {
        int row = tid >> 4, seg = tid & 15;
        const float* srow = S + row * SLDF + seg * 32;
        float mx = -1e30f;
        #pragma unroll
        for (int c = 0; c < 32; ++c) mx = fmaxf(mx, srow[c]);
        #pragma unroll
        for (int off = 1; off < 16; off <<= 1) mx = fmaxf(mx, __shfl_xor(mx, off));
        float sum = 0.f;
        u16* brow = Sb + row * SLDB + seg * 32;
        #pragma unroll
        for (int c = 0; c < 32; ++c) {
            float e = __expf(srow[c] - mx);
            sum += e;
            brow[c] = f2b(e);
        }
        #pragma unroll
        for (int off = 1; off < 16; off <<= 1) sum += __shfl_xor(sum, off);
        if (seg == 0) rowinv[row] = 1.0f / sum;
    }
    __syncthreads();

    // ---- PV: wave w computes output cols d in [w*16, w*16+16), K=512 ----
    const u16* vbase = VT + (long)((b * 16 + h) * 64 + wave * 16 + lrow) * 512;
    const u16* sbrow = Sb + lrow * SLDB;
    f32x4 oacc = {0.f, 0.f, 0.f, 0.f};
    #pragma unroll
    for (int ks = 0; ks < 16; ++ks) {
        bf16x8 ap = *(const bf16x8*)(sbrow + ks * 32 + lquad * 8);
        bf16x8 bp = *(const bf16x8*)(vbase + ks * 32 + lquad * 8);
        oacc = __builtin_amdgcn_mfma_f32_16x16x32_bf16(ap, bp, oacc, 0, 0, 0);
    }
    #pragma unroll
    for (int r = 0; r < 4; ++r) {
        int iloc = lquad * 4 + r;
        float val = oacc[r] * rowinv[iloc];
        attnOut[(long)(b * 256 + i0 + iloc) * 1024 + h * 64 + wave * 16 + lrow] = f2b(val);
    }
}

// ---------------- launch ----------------

extern "C" void kernel_launch(void* const* d_in, const int* in_sizes, int n_in,
                              void* d_out, int out_size, void* d_ws, size_t ws_size,
                              hipStream_t stream) {
    (void)in_sizes; (void)n_in; (void)out_size; (void)ws_size;
    const float* x    = (const float*)d_in[0];
    const float* h    = (const float*)d_in[1];
    const float* Wqkv = (const float*)d_in[2];
    const float* Wkr  = (const float*)d_in[3];
    const float* R    = (const float*)d_in[4];
    const float* u    = (const float*)d_in[5];
    const float* v    = (const float*)d_in[6];
    const float* Wout = (const float*)d_in[7];
    float* out = (float*)d_out;

    char* ws = (char*)d_ws;
    size_t off = 0;
    auto alloc = [&](size_t bytes) -> void* {
        void* p = ws + off;
        off = (off + bytes + 255) & ~(size_t)255;
        return p;
    };
    u16* catBF  = (u16*)alloc(4096L * 1024 * 2);   // [b*512][1024]
    u16* WqkvT  = (u16*)alloc(3072L * 1024 * 2);   // [3072][1024]
    u16* WkrT   = (u16*)alloc(1024L * 1024 * 2);
    u16* WoutT  = (u16*)alloc(1024L * 1024 * 2);
    u16* Rbf    = (u16*)alloc(1024L * 1024 * 2);
    u16* RW     = (u16*)alloc(1024L * 1024 * 2);   // [s][1024]
    u16* Qbf    = (u16*)alloc(16L * 8 * 256 * 64 * 2);   // [h][b][i][d]
    u16* Kt     = (u16*)alloc(8L * 16 * 512 * 64 * 2);   // [b][h][t][d]
    u16* VT     = (u16*)alloc(8L * 16 * 64 * 512 * 2);   // [b][h][d][t]
    u16* QR     = (u16*)alloc(16L * 2048 * 1024 * 2);    // [h][b*256+i][s]
    float* CKb  = (float*)alloc(8L * 16 * 512 * 4);
    float* VRb  = (float*)alloc(16L * 1024 * 4);
    u16* attnO  = (u16*)alloc(2048L * 1024 * 2);   // [b*256+i][h*64+d]

    // 1) casts / transposes
    cast_cat<<<16384, 256, 0, stream>>>(x, h, catBF);
    transpose_cast<<<dim3(96, 32), 256, 0, stream>>>(Wqkv, WqkvT, 1024, 3072);
    transpose_cast<<<dim3(32, 32), 256, 0, stream>>>(Wkr, WkrT, 1024, 1024);
    transpose_cast<<<dim3(32, 32), 256, 0, stream>>>(Wout, WoutT, 1024, 1024);
    cast_bf16<<<4096, 256, 0, stream>>>(R, Rbf);

    // 2) RW = R @ Wkr  (1024x1024x1024)
    gemm_bt<<<dim3(16, 16, 1), 256, 0, stream>>>(Rbf, 1024, 0L, WkrT, 1024, 0L, 1024,
                                                 EpiStoreBf{RW, 1024, 0});
    // 3) QKV = cat @ Wqkv  (4096x3072x1024), scatter epilogue
    gemm_bt<<<dim3(48, 64, 1), 256, 0, stream>>>(catBF, 1024, 0L, WqkvT, 1024, 0L, 1024,
                                                 EpiQKV{Qbf, Kt, VT});
    // 4) CK = u . K ; VR = v . RW
    ck_kernel<<<256, 256, 0, stream>>>(Kt, u, CKb);
    vr_kernel<<<64, 256, 0, stream>>>(RW, v, VRb);
    // 5) QR[h] = Q[h] @ RW[:, h*64:h*64+64]^T  (batched over h: M=2048, N=1024, K=64)
    gemm_bt<<<dim3(16, 32, 16), 256, 0, stream>>>(Qbf, 64, 2048L * 64, RW, 1024, 64L, 64,
                                                  EpiStoreBf{QR, 1024, 2048L * 1024});
    // 6) fused attention
    attn_kernel<<<dim3(16, 16, 8), 256, 0, stream>>>(Qbf, Kt, VT, QR, CKb, VRb, attnO);
    // 7) out = attnOut @ Wout  (2048x1024x1024), fp32 store
    gemm_bt<<<dim3(16, 32, 1), 256, 0, stream>>>(attnO, 1024, 0L, WoutT, 1024, 0L, 1024,
                                                 EpiStoreF32{out, 1024});
}

// Round 2
// 266.532 us; speedup vs baseline: 1.0963x; 1.0963x over previous
//
#include <hip/hip_runtime.h>
#include <hip/hip_bf16.h>
#include <math.h>

typedef unsigned short u16;
typedef short bf16x8 __attribute__((ext_vector_type(8)));
typedef float f32x4 __attribute__((ext_vector_type(4)));

__device__ __forceinline__ u16 f2b(float f) {
    __hip_bfloat16 h = __float2bfloat16(f);
    return *reinterpret_cast<u16*>(&h);
}
__device__ __forceinline__ float b2f(u16 v) {
    __hip_bfloat16 h;
    *reinterpret_cast<u16*>(&h) = v;
    return __bfloat162float(h);
}

__device__ __forceinline__ void gload_lds16(const void* g, void* l) {
    __builtin_amdgcn_global_load_lds(
        (const __attribute__((address_space(1))) void*)g,
        (__attribute__((address_space(3))) void*)l, 16, 0, 0);
}

// ---------------- cast / transpose kernels ----------------

__global__ __launch_bounds__(256) void cast_cat(const float* __restrict__ x,
                                                const float* __restrict__ h,
                                                u16* __restrict__ catBF) {
    int idx = blockIdx.x * 256 + threadIdx.x;      // < 4096*1024
    int c = idx & 1023, r = idx >> 10;
    int b = r >> 9, pos = r & 511;
    float v = (pos < 256) ? h[(b * 256 + pos) * 1024 + c]
                          : x[(b * 256 + pos - 256) * 1024 + c];
    catBF[idx] = f2b(v);
}

__global__ __launch_bounds__(256) void cast_bf16(const float* __restrict__ in,
                                                 u16* __restrict__ out) {
    int idx = blockIdx.x * 256 + threadIdx.x;
    out[idx] = f2b(in[idx]);
}

// W [K][N] f32 -> WT [N][K] bf16
__global__ __launch_bounds__(256) void transpose_cast(const float* __restrict__ W,
                                                      u16* __restrict__ WT,
                                                      int K, int N) {
    __shared__ float tile[32][33];
    int nb = blockIdx.x * 32, kb = blockIdx.y * 32;
    int tx = threadIdx.x & 31, ty = threadIdx.x >> 5;  // ty 0..7
    #pragma unroll
    for (int i = 0; i < 32; i += 8)
        tile[ty + i][tx] = W[(long)(kb + ty + i) * N + nb + tx];
    __syncthreads();
    #pragma unroll
    for (int i = 0; i < 32; i += 8)
        WT[(long)(nb + ty + i) * K + kb + tx] = f2b(tile[tx][ty + i]);
}

// RWg[r][c]: r<256 -> RW[768+r][c], else RW[0][c]   (only live shift rows)
__global__ __launch_bounds__(256) void gather_rwg(const u16* __restrict__ RW,
                                                  u16* __restrict__ RWg) {
    int idx = blockIdx.x * 256 + threadIdx.x;  // < 320*1024
    int r = idx >> 10, c = idx & 1023;
    int s = (r < 256) ? 768 + r : 0;
    RWg[idx] = RW[(long)s * 1024 + c];
}

// CK[b][h][j] = sum_d u[d] * K[b][h][j][d]
__global__ __launch_bounds__(256) void ck_kernel(const u16* __restrict__ Kt,
                                                 const float* __restrict__ u,
                                                 float* __restrict__ CK) {
    int idx = blockIdx.x * 256 + threadIdx.x;  // < 8*16*512
    const u16* kp = Kt + (long)idx * 64;
    float s = 0.f;
    #pragma unroll
    for (int d = 0; d < 64; ++d) s += u[d] * b2f(kp[d]);
    CK[idx] = s;
}

// VR[h][s] = sum_d v[d] * RW[s][h*64+d]
__global__ __launch_bounds__(256) void vr_kernel(const u16* __restrict__ RW,
                                                 const float* __restrict__ v,
                                                 float* __restrict__ VR) {
    int idx = blockIdx.x * 256 + threadIdx.x;  // < 16*1024
    int h = idx >> 10, s = idx & 1023;
    const u16* rp = RW + (long)s * 1024 + h * 64;
    float acc = 0.f;
    #pragma unroll
    for (int d = 0; d < 64; ++d) acc += v[d] * b2f(rp[d]);
    VR[idx] = acc;
}

// ---------------- epilogues ----------------

struct EpiQKV {  // scatter qkv into Q [h][b][i][d], K [b][h][t][d], V^T [b][h][d][t]
    u16 *Q, *Kt, *VT;
    __device__ void operator()(int z, int row, int col, float val) const {
        int b = row >> 9, pos = row & 511;
        int sec = col >> 10, cc = col & 1023;
        int head = cc >> 6, d = cc & 63;
        u16 bv = f2b(val);
        if (sec == 0) {
            if (pos >= 256)
                Q[(long)((head * 8 + b) * 256 + (pos - 256)) * 64 + d] = bv;
        } else if (sec == 1) {
            Kt[(long)((b * 16 + head) * 512 + pos) * 64 + d] = bv;
        } else {
            VT[(long)((b * 16 + head) * 64 + d) * 512 + pos] = bv;
        }
    }
};

struct EpiStoreBf {
    u16* C; long ldc; long strideZ;
    __device__ void operator()(int z, int row, int col, float val) const {
        C[(long)z * strideZ + (long)row * ldc + col] = f2b(val);
    }
};

struct EpiStoreF32 {
    float* C; long ldc;
    __device__ void operator()(int z, int row, int col, float val) const {
        C[(long)row * ldc + col] = val;
    }
};

// ---------------- 64x64-tile GEMM (C = A @ B^T), LDS-staged ----------------

template <typename Epi>
__global__ __launch_bounds__(256) void gemm_bt(const u16* __restrict__ A, int lda, long strideAz,
                                               const u16* __restrict__ B, int ldb, long strideBz,
                                               int K, Epi epi) {
    constexpr int LDT = 56;
    __shared__ alignas(16) u16 As[64 * LDT];
    __shared__ alignas(16) u16 Bs[64 * LDT];
    int n0 = blockIdx.x * 64, m0 = blockIdx.y * 64, z = blockIdx.z;
    const u16* Ab = A + (long)z * strideAz + (long)m0 * lda;
    const u16* Bb = B + (long)z * strideBz + (long)n0 * ldb;
    int tid = threadIdx.x;
    int wave = tid >> 6, lane = tid & 63;
    int wm = wave >> 1, wn = wave & 1;
    int lrow = lane & 15, lquad = lane >> 4;
    int srow = tid >> 2, scol = (tid & 3) * 8;
    f32x4 acc[2][2] = {};
    for (int k0 = 0; k0 < K; k0 += 32) {
        *(bf16x8*)(As + srow * LDT + scol) = *(const bf16x8*)(Ab + (long)srow * lda + k0 + scol);
        *(bf16x8*)(Bs + srow * LDT + scol) = *(const bf16x8*)(Bb + (long)srow * ldb + k0 + scol);
        __syncthreads();
        bf16x8 af[2], bfr[2];
        #pragma unroll
        for (int mt = 0; mt < 2; ++mt)
            af[mt] = *(const bf16x8*)(As + (wm * 32 + mt * 16 + lrow) * LDT + lquad * 8);
        #pragma unroll
        for (int nt = 0; nt < 2; ++nt)
            bfr[nt] = *(const bf16x8*)(Bs + (wn * 32 + nt * 16 + lrow) * LDT + lquad * 8);
        #pragma unroll
        for (int mt = 0; mt < 2; ++mt)
            #pragma unroll
            for (int nt = 0; nt < 2; ++nt)
                acc[mt][nt] = __builtin_amdgcn_mfma_f32_16x16x32_bf16(af[mt], bfr[nt], acc[mt][nt], 0, 0, 0);
        __syncthreads();
    }
    #pragma unroll
    for (int mt = 0; mt < 2; ++mt)
        #pragma unroll
        for (int nt = 0; nt < 2; ++nt)
            #pragma unroll
            for (int r = 0; r < 4; ++r) {
                int row = m0 + wm * 32 + mt * 16 + lquad * 4 + r;
                int col = n0 + wn * 32 + nt * 16 + lrow;
                epi(z, row, col, acc[mt][nt][r]);
            }
}

// ---------------- 128x128-tile GEMM (m97 structure: global_load_lds) ----------------
// 256 threads = 4 waves (2x2), each wave computes 64x64 via 4x4 MFMAs.
// LDS tiles [128][32] bf16 contiguous (global_load_lds: wave-uniform base + lane*16).

template <typename Epi>
__global__ __launch_bounds__(256) void gemm128(const u16* __restrict__ A, int lda,
                                               const u16* __restrict__ B, int ldb,
                                               int K, Epi epi) {
    __shared__ alignas(16) u16 As[128 * 32];
    __shared__ alignas(16) u16 Bs[128 * 32];
    int n0 = blockIdx.x * 128, m0 = blockIdx.y * 128;
    int tid = threadIdx.x, wave = tid >> 6, lane = tid & 63;
    int wm = wave >> 1, wn = wave & 1;
    int lrow = lane & 15, lquad = lane >> 4;
    int grow = tid >> 2, gcol = (tid & 3) * 8;   // staging: row tid/4, col-group tid%4
    const u16* Ab = A + (long)m0 * lda;
    const u16* Bb = B + (long)n0 * ldb;
    f32x4 acc[4][4] = {};
    for (int k0 = 0; k0 < K; k0 += 32) {
        gload_lds16(Ab + (long)grow * lda + k0 + gcol,        As + grow * 32 + gcol);
        gload_lds16(Ab + (long)(grow + 64) * lda + k0 + gcol, As + (grow + 64) * 32 + gcol);
        gload_lds16(Bb + (long)grow * ldb + k0 + gcol,        Bs + grow * 32 + gcol);
        gload_lds16(Bb + (long)(grow + 64) * ldb + k0 + gcol, Bs + (grow + 64) * 32 + gcol);
        __syncthreads();
        bf16x8 af[4], bfr[4];
        #pragma unroll
        for (int mt = 0; mt < 4; ++mt)
            af[mt] = *(const bf16x8*)(As + (wm * 64 + mt * 16 + lrow) * 32 + lquad * 8);
        #pragma unroll
        for (int nt = 0; nt < 4; ++nt)
            bfr[nt] = *(const bf16x8*)(Bs + (wn * 64 + nt * 16 + lrow) * 32 + lquad * 8);
        #pragma unroll
        for (int mt = 0; mt < 4; ++mt)
            #pragma unroll
            for (int nt = 0; nt < 4; ++nt)
                acc[mt][nt] = __builtin_amdgcn_mfma_f32_16x16x32_bf16(af[mt], bfr[nt], acc[mt][nt], 0, 0, 0);
        __syncthreads();
    }
    #pragma unroll
    for (int mt = 0; mt < 4; ++mt)
        #pragma unroll
        for (int nt = 0; nt < 4; ++nt)
            #pragma unroll
            for (int r = 0; r < 4; ++r) {
                int row = m0 + wm * 64 + mt * 16 + lquad * 4 + r;
                int col = n0 + wn * 64 + nt * 16 + lrow;
                epi(0, row, col, acc[mt][nt][r]);
            }
}

// ---------------- fused attention ----------------
__global__ __launch_bounds__(256) void attn_kernel(const u16* __restrict__ Qbf,
                                                   const u16* __restrict__ Kt,
                                                   const u16* __restrict__ VT,
                                                   const u16* __restrict__ QR,
                                                   const float* __restrict__ CK,
                                                   const float* __restrict__ VR,
                                                   u16* __restrict__ attnOut) {
    constexpr int SLDF = 516;
    constexpr int SLDB = 520;
    __shared__ alignas(16) float S[16 * SLDF];
    __shared__ alignas(16) u16 Sb[16 * SLDB];
    __shared__ float rowinv[16];
    int i0 = blockIdx.x * 16;
    int h = blockIdx.y, b = blockIdx.z;
    int tid = threadIdx.x, wave = tid >> 6, lane = tid & 63;
    int lrow = lane & 15, lquad = lane >> 4;

    const u16* qbase = Qbf + (long)((h * 8 + b) * 256 + i0 + lrow) * 64;
    bf16x8 aq0 = *(const bf16x8*)(qbase + lquad * 8);
    bf16x8 aq1 = *(const bf16x8*)(qbase + 32 + lquad * 8);

    const u16* kbase = Kt + (long)((b * 16 + h) * 512) * 64;
    const float* ckbase = CK + (b * 16 + h) * 512;
    const u16* qrbase = QR + (long)((h * 8 + b) * 256) * 320;   // compact: 320 cols
    const float* vrbase = VR + h * 1024;

    for (int jt = 0; jt < 8; ++jt) {
        int j0 = wave * 128 + jt * 16;
        const u16* kp = kbase + (long)(j0 + lrow) * 64;
        bf16x8 bk0 = *(const bf16x8*)(kp + lquad * 8);
        bf16x8 bk1 = *(const bf16x8*)(kp + 32 + lquad * 8);
        f32x4 acc = {0.f, 0.f, 0.f, 0.f};
        acc = __builtin_amdgcn_mfma_f32_16x16x32_bf16(aq0, bk0, acc, 0, 0, 0);
        acc = __builtin_amdgcn_mfma_f32_16x16x32_bf16(aq1, bk1, acc, 0, 0, 0);
        int j = j0 + lrow;
        float ck = ckbase[j];
        #pragma unroll
        for (int r = 0; r < 4; ++r) {
            int iloc = lquad * 4 + r;
            int i = i0 + iloc;
            int s = (j - i - 256) & 1023;
            int sc = (s >= 768) ? (s - 768) : 256;   // live s are {0} u [768,1023]
            float val = acc[r] + ck + b2f(qrbase[(long)i * 320 + sc]) + vrbase[s];
            bool ok = (j >= 256) ? ((j - 256) <= i) : (j >= i);
            S[iloc * SLDF + j] = ok ? val * 0.125f : -1e30f;
        }
    }
    __syncthreads();

    {
        int row = tid >> 4, seg = tid & 15;
        const float* srow = S + row * SLDF + seg * 32;
        float mx = -1e30f;
        #pragma unroll
        for (int c = 0; c < 32; ++c) mx = fmaxf(mx, srow[c]);
        #pragma unroll
        for (int off = 1; off < 16; off <<= 1) mx = fmaxf(mx, __shfl_xor(mx, off));
        float sum = 0.f;
        u16* brow = Sb + row * SLDB + seg * 32;
        #pragma unroll
        for (int c = 0; c < 32; ++c) {
            float e = __expf(srow[c] - mx);
            sum += e;
            brow[c] = f2b(e);
        }
        #pragma unroll
        for (int off = 1; off < 16; off <<= 1) sum += __shfl_xor(sum, off);
        if (seg == 0) rowinv[row] = 1.0f / sum;
    }
    __syncthreads();

    const u16* vbase = VT + (long)((b * 16 + h) * 64 + wave * 16 + lrow) * 512;
    const u16* sbrow = Sb + lrow * SLDB;
    f32x4 oacc = {0.f, 0.f, 0.f, 0.f};
    #pragma unroll
    for (int ks = 0; ks < 16; ++ks) {
        bf16x8 ap = *(const bf16x8*)(sbrow + ks * 32 + lquad * 8);
        bf16x8 bp = *(const bf16x8*)(vbase + ks * 32 + lquad * 8);
        oacc = __builtin_amdgcn_mfma_f32_16x16x32_bf16(ap, bp, oacc, 0, 0, 0);
    }
    #pragma unroll
    for (int r = 0; r < 4; ++r) {
        int iloc = lquad * 4 + r;
        float val = oacc[r] * rowinv[iloc];
        attnOut[(long)(b * 256 + i0 + iloc) * 1024 + h * 64 + wave * 16 + lrow] = f2b(val);
    }
}

// ---------------- launch ----------------

extern "C" void kernel_launch(void* const* d_in, const int* in_sizes, int n_in,
                              void* d_out, int out_size, void* d_ws, size_t ws_size,
                              hipStream_t stream) {
    (void)in_sizes; (void)n_in; (void)out_size; (void)ws_size;
    const float* x    = (const float*)d_in[0];
    const float* h    = (const float*)d_in[1];
    const float* Wqkv = (const float*)d_in[2];
    const float* Wkr  = (const float*)d_in[3];
    const float* R    = (const float*)d_in[4];
    const float* u    = (const float*)d_in[5];
    const float* v    = (const float*)d_in[6];
    const float* Wout = (const float*)d_in[7];
    float* out = (float*)d_out;

    char* ws = (char*)d_ws;
    size_t off = 0;
    auto alloc = [&](size_t bytes) -> void* {
        void* p = ws + off;
        off = (off + bytes + 255) & ~(size_t)255;
        return p;
    };
    u16* catBF  = (u16*)alloc(4096L * 1024 * 2);   // [b*512][1024]
    u16* WqkvT  = (u16*)alloc(3072L * 1024 * 2);   // [3072][1024]
    u16* WkrT   = (u16*)alloc(1024L * 1024 * 2);
    u16* WoutT  = (u16*)alloc(1024L * 1024 * 2);
    u16* Rbf    = (u16*)alloc(1024L * 1024 * 2);
    u16* RW     = (u16*)alloc(1024L * 1024 * 2);   // [s][1024]
    u16* RWg    = (u16*)alloc(320L * 1024 * 2);    // gathered live shift rows
    u16* Qbf    = (u16*)alloc(16L * 8 * 256 * 64 * 2);   // [h][b][i][d]
    u16* Kt     = (u16*)alloc(8L * 16 * 512 * 64 * 2);   // [b][h][t][d]
    u16* VT     = (u16*)alloc(8L * 16 * 64 * 512 * 2);   // [b][h][d][t]
    u16* QR     = (u16*)alloc(16L * 2048 * 320 * 2);     // [h][b*256+i][sc]
    float* CKb  = (float*)alloc(8L * 16 * 512 * 4);
    float* VRb  = (float*)alloc(16L * 1024 * 4);
    u16* attnO  = (u16*)alloc(2048L * 1024 * 2);   // [b*256+i][h*64+d]

    cast_cat<<<16384, 256, 0, stream>>>(x, h, catBF);
    transpose_cast<<<dim3(96, 32), 256, 0, stream>>>(Wqkv, WqkvT, 1024, 3072);
    transpose_cast<<<dim3(32, 32), 256, 0, stream>>>(Wkr, WkrT, 1024, 1024);
    transpose_cast<<<dim3(32, 32), 256, 0, stream>>>(Wout, WoutT, 1024, 1024);
    cast_bf16<<<4096, 256, 0, stream>>>(R, Rbf);

    // RW = R @ Wkr  (1024x1024x1024)
    gemm_bt<<<dim3(16, 16, 1), 256, 0, stream>>>(Rbf, 1024, 0L, WkrT, 1024, 0L, 1024,
                                                 EpiStoreBf{RW, 1024, 0});
    gather_rwg<<<1280, 256, 0, stream>>>(RW, RWg);
    // QKV = cat @ Wqkv  (4096x3072x1024) — 128-tile m97 structure
    gemm128<<<dim3(24, 32), 256, 0, stream>>>(catBF, 1024, WqkvT, 1024, 1024,
                                              EpiQKV{Qbf, Kt, VT});
    ck_kernel<<<256, 256, 0, stream>>>(Kt, u, CKb);
    vr_kernel<<<64, 256, 0, stream>>>(RW, v, VRb);
    // QR[h] = Q[h] @ RWg[:, h*64:h*64+64]^T  (M=2048, N=320, K=64, batched over h)
    gemm_bt<<<dim3(5, 32, 16), 256, 0, stream>>>(Qbf, 64, 2048L * 64, RWg, 1024, 64L, 64,
                                                 EpiStoreBf{QR, 320, 2048L * 320});
    attn_kernel<<<dim3(16, 16, 8), 256, 0, stream>>>(Qbf, Kt, VT, QR, CKb, VRb, attnO);
    // out = attnOut @ Wout  (2048x1024x1024)
    gemm_bt<<<dim3(16, 32, 1), 256, 0, stream>>>(attnO, 1024, 0L, WoutT, 1024, 0L, 1024,
                                                 EpiStoreF32{out, 1024});
}

// Round 3
// 253.361 us; speedup vs baseline: 1.1533x; 1.0520x over previous
//
#include <hip/hip_runtime.h>
#include <hip/hip_bf16.h>
#include <math.h>

typedef unsigned short u16;
typedef short bf16x8 __attribute__((ext_vector_type(8)));
typedef float f32x4 __attribute__((ext_vector_type(4)));

__device__ __forceinline__ u16 f2b(float f) {
    __hip_bfloat16 h = __float2bfloat16(f);
    return *reinterpret_cast<u16*>(&h);
}
__device__ __forceinline__ float b2f(u16 v) {
    __hip_bfloat16 h;
    *reinterpret_cast<u16*>(&h) = v;
    return __bfloat162float(h);
}

__device__ __forceinline__ void gload_lds16(const void* g, void* l) {
    __builtin_amdgcn_global_load_lds(
        (const __attribute__((address_space(1))) void*)g,
        (__attribute__((address_space(3))) void*)l, 16, 0, 0);
}

// ---------------- cast / transpose kernels ----------------

__global__ __launch_bounds__(256) void cast_cat(const float* __restrict__ x,
                                                const float* __restrict__ h,
                                                u16* __restrict__ catBF) {
    int idx = blockIdx.x * 256 + threadIdx.x;      // < 4096*1024
    int c = idx & 1023, r = idx >> 10;
    int b = r >> 9, pos = r & 511;
    float v = (pos < 256) ? h[(b * 256 + pos) * 1024 + c]
                          : x[(b * 256 + pos - 256) * 1024 + c];
    catBF[idx] = f2b(v);
}

__global__ __launch_bounds__(256) void cast_bf16(const float* __restrict__ in,
                                                 u16* __restrict__ out) {
    int idx = blockIdx.x * 256 + threadIdx.x;
    out[idx] = f2b(in[idx]);
}

// W [K][N] f32 -> WT [N][K] bf16
__global__ __launch_bounds__(256) void transpose_cast(const float* __restrict__ W,
                                                      u16* __restrict__ WT,
                                                      int K, int N) {
    __shared__ float tile[32][33];
    int nb = blockIdx.x * 32, kb = blockIdx.y * 32;
    int tx = threadIdx.x & 31, ty = threadIdx.x >> 5;
    #pragma unroll
    for (int i = 0; i < 32; i += 8)
        tile[ty + i][tx] = W[(long)(kb + ty + i) * N + nb + tx];
    __syncthreads();
    #pragma unroll
    for (int i = 0; i < 32; i += 8)
        WT[(long)(nb + ty + i) * K + kb + tx] = f2b(tile[tx][ty + i]);
}

// RWg[r][c]: r<256 -> RW[768+r][c], else RW[0][c]   (only live shift rows)
__global__ __launch_bounds__(256) void gather_rwg(const u16* __restrict__ RW,
                                                  u16* __restrict__ RWg) {
    int idx = blockIdx.x * 256 + threadIdx.x;  // < 320*1024
    int r = idx >> 10, c = idx & 1023;
    int s = (r < 256) ? 768 + r : 0;
    RWg[idx] = RW[(long)s * 1024 + c];
}

// ---------------- epilogues ----------------

// scatter qkv: Qu/Qv [h][b][i][d] (q + u, q + v), K [b][h][t][d], V^T [b][h][d][t]
struct EpiQKV {
    u16 *Qu, *Qv, *Kt, *VT;
    const float *u, *v;
    __device__ void operator()(int z, int row, int col, float val) const {
        int b = row >> 9, pos = row & 511;
        int sec = col >> 10, cc = col & 1023;
        int head = cc >> 6, d = cc & 63;
        if (sec == 0) {
            if (pos >= 256) {
                long qi = (long)((head * 8 + b) * 256 + (pos - 256)) * 64 + d;
                Qu[qi] = f2b(val + u[d]);
                Qv[qi] = f2b(val + v[d]);
            }
        } else if (sec == 1) {
            Kt[(long)((b * 16 + head) * 512 + pos) * 64 + d] = f2b(val);
        } else {
            VT[(long)((b * 16 + head) * 64 + d) * 512 + pos] = f2b(val);
        }
    }
};

struct EpiStoreBf {
    u16* C; long ldc; long strideZ;
    __device__ void operator()(int z, int row, int col, float val) const {
        C[(long)z * strideZ + (long)row * ldc + col] = f2b(val);
    }
};

struct EpiStoreF32 {
    float* C; long ldc;
    __device__ void operator()(int z, int row, int col, float val) const {
        C[(long)row * ldc + col] = val;
    }
};

// ---------------- 64x64-tile GEMM (C = A @ B^T), LDS-staged ----------------

template <typename Epi>
__global__ __launch_bounds__(256) void gemm_bt(const u16* __restrict__ A, int lda, long strideAz,
                                               const u16* __restrict__ B, int ldb, long strideBz,
                                               int K, Epi epi) {
    constexpr int LDT = 56;
    __shared__ alignas(16) u16 As[64 * LDT];
    __shared__ alignas(16) u16 Bs[64 * LDT];
    int n0 = blockIdx.x * 64, m0 = blockIdx.y * 64, z = blockIdx.z;
    const u16* Ab = A + (long)z * strideAz + (long)m0 * lda;
    const u16* Bb = B + (long)z * strideBz + (long)n0 * ldb;
    int tid = threadIdx.x;
    int wave = tid >> 6, lane = tid & 63;
    int wm = wave >> 1, wn = wave & 1;
    int lrow = lane & 15, lquad = lane >> 4;
    int srow = tid >> 2, scol = (tid & 3) * 8;
    f32x4 acc[2][2] = {};
    for (int k0 = 0; k0 < K; k0 += 32) {
        *(bf16x8*)(As + srow * LDT + scol) = *(const bf16x8*)(Ab + (long)srow * lda + k0 + scol);
        *(bf16x8*)(Bs + srow * LDT + scol) = *(const bf16x8*)(Bb + (long)srow * ldb + k0 + scol);
        __syncthreads();
        bf16x8 af[2], bfr[2];
        #pragma unroll
        for (int mt = 0; mt < 2; ++mt)
            af[mt] = *(const bf16x8*)(As + (wm * 32 + mt * 16 + lrow) * LDT + lquad * 8);
        #pragma unroll
        for (int nt = 0; nt < 2; ++nt)
            bfr[nt] = *(const bf16x8*)(Bs + (wn * 32 + nt * 16 + lrow) * LDT + lquad * 8);
        #pragma unroll
        for (int mt = 0; mt < 2; ++mt)
            #pragma unroll
            for (int nt = 0; nt < 2; ++nt)
                acc[mt][nt] = __builtin_amdgcn_mfma_f32_16x16x32_bf16(af[mt], bfr[nt], acc[mt][nt], 0, 0, 0);
        __syncthreads();
    }
    #pragma unroll
    for (int mt = 0; mt < 2; ++mt)
        #pragma unroll
        for (int nt = 0; nt < 2; ++nt)
            #pragma unroll
            for (int r = 0; r < 4; ++r) {
                int row = m0 + wm * 32 + mt * 16 + lquad * 4 + r;
                int col = n0 + wn * 32 + nt * 16 + lrow;
                epi(z, row, col, acc[mt][nt][r]);
            }
}

// ---------------- 128x128-tile GEMM (m97 structure: global_load_lds) ----------------

template <typename Epi>
__global__ __launch_bounds__(256) void gemm128(const u16* __restrict__ A, int lda,
                                               const u16* __restrict__ B, int ldb,
                                               int K, Epi epi) {
    __shared__ alignas(16) u16 As[128 * 32];
    __shared__ alignas(16) u16 Bs[128 * 32];
    int n0 = blockIdx.x * 128, m0 = blockIdx.y * 128;
    int tid = threadIdx.x, wave = tid >> 6, lane = tid & 63;
    int wm = wave >> 1, wn = wave & 1;
    int lrow = lane & 15, lquad = lane >> 4;
    int grow = tid >> 2, gcol = (tid & 3) * 8;
    const u16* Ab = A + (long)m0 * lda;
    const u16* Bb = B + (long)n0 * ldb;
    f32x4 acc[4][4] = {};
    for (int k0 = 0; k0 < K; k0 += 32) {
        gload_lds16(Ab + (long)grow * lda + k0 + gcol,        As + grow * 32 + gcol);
        gload_lds16(Ab + (long)(grow + 64) * lda + k0 + gcol, As + (grow + 64) * 32 + gcol);
        gload_lds16(Bb + (long)grow * ldb + k0 + gcol,        Bs + grow * 32 + gcol);
        gload_lds16(Bb + (long)(grow + 64) * ldb + k0 + gcol, Bs + (grow + 64) * 32 + gcol);
        __syncthreads();
        bf16x8 af[4], bfr[4];
        #pragma unroll
        for (int mt = 0; mt < 4; ++mt)
            af[mt] = *(const bf16x8*)(As + (wm * 64 + mt * 16 + lrow) * 32 + lquad * 8);
        #pragma unroll
        for (int nt = 0; nt < 4; ++nt)
            bfr[nt] = *(const bf16x8*)(Bs + (wn * 64 + nt * 16 + lrow) * 32 + lquad * 8);
        #pragma unroll
        for (int mt = 0; mt < 4; ++mt)
            #pragma unroll
            for (int nt = 0; nt < 4; ++nt)
                acc[mt][nt] = __builtin_amdgcn_mfma_f32_16x16x32_bf16(af[mt], bfr[nt], acc[mt][nt], 0, 0, 0);
        __syncthreads();
    }
    #pragma unroll
    for (int mt = 0; mt < 4; ++mt)
        #pragma unroll
        for (int nt = 0; nt < 4; ++nt)
            #pragma unroll
            for (int r = 0; r < 4; ++r) {
                int row = m0 + wm * 64 + mt * 16 + lquad * 4 + r;
                int col = n0 + wn * 64 + nt * 16 + lrow;
                epi(0, row, col, acc[mt][nt][r]);
            }
}

// ---------------- fused attention (register softmax) ----------------
// grid: 2048 1-D blocks, id = it*128 + bh so all 16 i-tiles of one (b,h)
// land on one XCD (id%8 = bh%8) -> K/V slices stay L2-resident.
// 256 threads = 4 waves; wave w owns j in [w*128, w*128+128).
__global__ __launch_bounds__(256) void attn_kernel(const u16* __restrict__ Qu,
                                                   const u16* __restrict__ Kt,
                                                   const u16* __restrict__ VT,
                                                   const u16* __restrict__ QR,
                                                   u16* __restrict__ attnOut) {
    constexpr int SLDB = 520;   // u16 stride: 2-way bank alias on b128 reads (free)
    __shared__ alignas(16) u16 Sb[16 * SLDB];
    __shared__ float red[2][4][16];   // [max/sum][wave][row]
    int id = blockIdx.x;
    int bh = id & 127, it = id >> 7;
    int b = bh >> 4, h = bh & 15;
    int i0 = it * 16;
    int tid = threadIdx.x, wave = tid >> 6, lane = tid & 63;
    int lrow = lane & 15, lquad = lane >> 4;

    const u16* qbase = Qu + (long)((h * 8 + b) * 256 + i0 + lrow) * 64;
    bf16x8 aq0 = *(const bf16x8*)(qbase + lquad * 8);
    bf16x8 aq1 = *(const bf16x8*)(qbase + 32 + lquad * 8);

    const u16* kbase = Kt + (long)(bh * 512) * 64;
    const u16* qrbase = QR + ((long)h * 2048 + b * 256) * 320;

    // ---- QK^T into registers ----
    f32x4 acc[8];
    #pragma unroll
    for (int jt = 0; jt < 8; ++jt) {
        const u16* kp = kbase + (long)(wave * 128 + jt * 16 + lrow) * 64;
        bf16x8 bk0 = *(const bf16x8*)(kp + lquad * 8);
        bf16x8 bk1 = *(const bf16x8*)(kp + 32 + lquad * 8);
        f32x4 a = {0.f, 0.f, 0.f, 0.f};
        a = __builtin_amdgcn_mfma_f32_16x16x32_bf16(aq0, bk0, a, 0, 0, 0);
        a = __builtin_amdgcn_mfma_f32_16x16x32_bf16(aq1, bk1, a, 0, 0, 0);
        acc[jt] = a;
    }

    // ---- add rel-term, mask, scale; per-lane row max ----
    float m4[4] = {-1e30f, -1e30f, -1e30f, -1e30f};
    #pragma unroll
    for (int jt = 0; jt < 8; ++jt) {
        int j = wave * 128 + jt * 16 + lrow;
        #pragma unroll
        for (int r = 0; r < 4; ++r) {
            int iloc = lquad * 4 + r;
            int i = i0 + iloc;
            int s = (j - i - 256) & 1023;
            int sc = (s >= 768) ? (s - 768) : 256;   // live s in {0} u [768,1023]
            bool ok = (j >= 256) ? ((j - 256) <= i) : (j >= i);
            float val = ok ? (acc[jt][r] + b2f(qrbase[(long)(i0 + iloc) * 320 + sc])) * 0.125f
                           : -1e30f;
            acc[jt][r] = val;
            m4[r] = fmaxf(m4[r], val);
        }
    }
    // reduce over the 16 lanes sharing lquad (xor of low 4 lane bits)
    #pragma unroll
    for (int r = 0; r < 4; ++r)
        #pragma unroll
        for (int off = 1; off < 16; off <<= 1)
            m4[r] = fmaxf(m4[r], __shfl_xor(m4[r], off));
    if (lrow == 0)
        #pragma unroll
        for (int r = 0; r < 4; ++r) red[0][wave][lquad * 4 + r] = m4[r];
    __syncthreads();

    float gmax[4];
    #pragma unroll
    for (int r = 0; r < 4; ++r) {
        int row = lquad * 4 + r;
        gmax[r] = fmaxf(fmaxf(red[0][0][row], red[0][1][row]),
                        fmaxf(red[0][2][row], red[0][3][row]));
    }

    // ---- exp, write bf16 probs, per-lane row sums ----
    float s4[4] = {0.f, 0.f, 0.f, 0.f};
    #pragma unroll
    for (int jt = 0; jt < 8; ++jt) {
        int j = wave * 128 + jt * 16 + lrow;
        #pragma unroll
        for (int r = 0; r < 4; ++r) {
            float p = __expf(acc[jt][r] - gmax[r]);
            s4[r] += p;
            Sb[(lquad * 4 + r) * SLDB + j] = f2b(p);
        }
    }
    #pragma unroll
    for (int r = 0; r < 4; ++r)
        #pragma unroll
        for (int off = 1; off < 16; off <<= 1)
            s4[r] += __shfl_xor(s4[r], off);
    if (lrow == 0)
        #pragma unroll
        for (int r = 0; r < 4; ++r) red[1][wave][lquad * 4 + r] = s4[r];
    __syncthreads();

    // ---- PV: wave w computes output cols d in [w*16, w*16+16), K=512 ----
    const u16* vbase = VT + (long)(bh * 64 + wave * 16 + lrow) * 512;
    const u16* sbrow = Sb + lrow * SLDB;
    f32x4 oacc = {0.f, 0.f, 0.f, 0.f};
    #pragma unroll
    for (int ks = 0; ks < 16; ++ks) {
        bf16x8 ap = *(const bf16x8*)(sbrow + ks * 32 + lquad * 8);
        bf16x8 bp = *(const bf16x8*)(vbase + ks * 32 + lquad * 8);
        oacc = __builtin_amdgcn_mfma_f32_16x16x32_bf16(ap, bp, oacc, 0, 0, 0);
    }
    #pragma unroll
    for (int r = 0; r < 4; ++r) {
        int row = lquad * 4 + r;
        float inv = 1.0f / (red[1][0][row] + red[1][1][row] + red[1][2][row] + red[1][3][row]);
        attnOut[(long)(b * 256 + i0 + row) * 1024 + h * 64 + wave * 16 + lrow] = f2b(oacc[r] * inv);
    }
}

// ---------------- launch ----------------

extern "C" void kernel_launch(void* const* d_in, const int* in_sizes, int n_in,
                              void* d_out, int out_size, void* d_ws, size_t ws_size,
                              hipStream_t stream) {
    (void)in_sizes; (void)n_in; (void)out_size; (void)ws_size;
    const float* x    = (const float*)d_in[0];
    const float* h    = (const float*)d_in[1];
    const float* Wqkv = (const float*)d_in[2];
    const float* Wkr  = (const float*)d_in[3];
    const float* R    = (const float*)d_in[4];
    const float* u    = (const float*)d_in[5];
    const float* v    = (const float*)d_in[6];
    const float* Wout = (const float*)d_in[7];
    float* out = (float*)d_out;

    char* ws = (char*)d_ws;
    size_t off = 0;
    auto alloc = [&](size_t bytes) -> void* {
        void* p = ws + off;
        off = (off + bytes + 255) & ~(size_t)255;
        return p;
    };
    u16* catBF  = (u16*)alloc(4096L * 1024 * 2);   // [b*512][1024]
    u16* WqkvT  = (u16*)alloc(3072L * 1024 * 2);
    u16* WkrT   = (u16*)alloc(1024L * 1024 * 2);
    u16* WoutT  = (u16*)alloc(1024L * 1024 * 2);
    u16* Rbf    = (u16*)alloc(1024L * 1024 * 2);
    u16* RW     = (u16*)alloc(1024L * 1024 * 2);   // [s][1024]
    u16* RWg    = (u16*)alloc(320L * 1024 * 2);    // live shift rows
    u16* Qu     = (u16*)alloc(16L * 8 * 256 * 64 * 2);   // [h][b][i][d], q + u
    u16* Qv     = (u16*)alloc(16L * 8 * 256 * 64 * 2);   // q + v
    u16* Kt     = (u16*)alloc(8L * 16 * 512 * 64 * 2);   // [b][h][t][d]
    u16* VT     = (u16*)alloc(8L * 16 * 64 * 512 * 2);   // [b][h][d][t]
    u16* QR     = (u16*)alloc(16L * 2048 * 320 * 2);     // [h][b*256+i][sc]
    u16* attnO  = (u16*)alloc(2048L * 1024 * 2);   // [b*256+i][h*64+d]

    cast_cat<<<16384, 256, 0, stream>>>(x, h, catBF);
    transpose_cast<<<dim3(96, 32), 256, 0, stream>>>(Wqkv, WqkvT, 1024, 3072);
    transpose_cast<<<dim3(32, 32), 256, 0, stream>>>(Wkr, WkrT, 1024, 1024);
    transpose_cast<<<dim3(32, 32), 256, 0, stream>>>(Wout, WoutT, 1024, 1024);
    cast_bf16<<<4096, 256, 0, stream>>>(R, Rbf);

    // RW = R @ Wkr  (1024x1024x1024)
    gemm_bt<<<dim3(16, 16, 1), 256, 0, stream>>>(Rbf, 1024, 0L, WkrT, 1024, 0L, 1024,
                                                 EpiStoreBf{RW, 1024, 0});
    gather_rwg<<<1280, 256, 0, stream>>>(RW, RWg);
    // QKV = cat @ Wqkv  (4096x3072x1024), scatter + u/v fold epilogue
    gemm128<<<dim3(24, 32), 256, 0, stream>>>(catBF, 1024, WqkvT, 1024, 1024,
                                              EpiQKV{Qu, Qv, Kt, VT, u, v});
    // QR[h] = (Q+v)[h] @ RWg[:, h*64:h*64+64]^T  (M=2048, N=320, K=64)
    gemm_bt<<<dim3(5, 32, 16), 256, 0, stream>>>(Qv, 64, 2048L * 64, RWg, 1024, 64L, 64,
                                                 EpiStoreBf{QR, 320, 2048L * 320});
    attn_kernel<<<2048, 256, 0, stream>>>(Qu, Kt, VT, QR, attnO);
    // out = attnOut @ Wout  (2048x1024x1024)
    gemm_bt<<<dim3(16, 32, 1), 256, 0, stream>>>(attnO, 1024, 0L, WoutT, 1024, 0L, 1024,
                                                 EpiStoreF32{out, 1024});
}

// Round 4
// 250.155 us; speedup vs baseline: 1.1681x; 1.0128x over previous
//
#include <hip/hip_runtime.h>
#include <hip/hip_bf16.h>
#include <math.h>

typedef unsigned short u16;
typedef short bf16x8 __attribute__((ext_vector_type(8)));
typedef float f32x4 __attribute__((ext_vector_type(4)));

__device__ __forceinline__ u16 f2b(float f) {
    __hip_bfloat16 h = __float2bfloat16(f);
    return *reinterpret_cast<u16*>(&h);
}
__device__ __forceinline__ float b2f(u16 v) {
    __hip_bfloat16 h;
    *reinterpret_cast<u16*>(&h) = v;
    return __bfloat162float(h);
}

__device__ __forceinline__ void gload_lds16(const void* g, void* l) {
    __builtin_amdgcn_global_load_lds(
        (const __attribute__((address_space(1))) void*)g,
        (__attribute__((address_space(3))) void*)l, 16, 0, 0);
}

// ---------------- cast / transpose kernels ----------------

__global__ __launch_bounds__(256) void cast_cat(const float* __restrict__ x,
                                                const float* __restrict__ h,
                                                u16* __restrict__ catBF) {
    int idx = blockIdx.x * 256 + threadIdx.x;      // < 4096*1024
    int c = idx & 1023, r = idx >> 10;
    int b = r >> 9, pos = r & 511;
    float v = (pos < 256) ? h[(b * 256 + pos) * 1024 + c]
                          : x[(b * 256 + pos - 256) * 1024 + c];
    catBF[idx] = f2b(v);
}

// W [K][N] f32 -> WT [N][K] bf16
__global__ __launch_bounds__(256) void transpose_cast(const float* __restrict__ W,
                                                      u16* __restrict__ WT,
                                                      int K, int N) {
    __shared__ float tile[32][33];
    int nb = blockIdx.x * 32, kb = blockIdx.y * 32;
    int tx = threadIdx.x & 31, ty = threadIdx.x >> 5;
    #pragma unroll
    for (int i = 0; i < 32; i += 8)
        tile[ty + i][tx] = W[(long)(kb + ty + i) * N + nb + tx];
    __syncthreads();
    #pragma unroll
    for (int i = 0; i < 32; i += 8)
        WT[(long)(nb + ty + i) * K + kb + tx] = f2b(tile[tx][ty + i]);
}

// Vtmp [bh][t][d] -> VT [bh][d][t]  (LDS-tiled, coalesced both sides)
__global__ __launch_bounds__(256) void transpose_v(const u16* __restrict__ Vtmp,
                                                   u16* __restrict__ VT) {
    __shared__ u16 tile[32][34];
    int t0 = blockIdx.x * 32, d0 = blockIdx.y * 32, bh = blockIdx.z;
    int tx = threadIdx.x & 31, ty = threadIdx.x >> 5;
    const u16* src = Vtmp + (long)bh * 512 * 64;
    #pragma unroll
    for (int i = 0; i < 32; i += 8)
        tile[ty + i][tx] = src[(long)(t0 + ty + i) * 64 + d0 + tx];
    __syncthreads();
    u16* dst = VT + (long)bh * 64 * 512;
    #pragma unroll
    for (int i = 0; i < 32; i += 8)
        dst[(long)(d0 + ty + i) * 512 + t0 + tx] = tile[tx][ty + i];
}

// RWg[r][c]: r<256 -> RW[768+r][c], else RW[0][c]   (only live shift rows)
__global__ __launch_bounds__(256) void gather_rwg(const u16* __restrict__ RW,
                                                  u16* __restrict__ RWg) {
    int idx = blockIdx.x * 256 + threadIdx.x;  // < 320*1024
    int r = idx >> 10, c = idx & 1023;
    int s = (r < 256) ? 768 + r : 0;
    RWg[idx] = RW[(long)s * 1024 + c];
}

// ---------------- epilogues ----------------

// scatter qkv: Q [h][b][i][d] (scaled 0.125), K [b][h][t][d], Vtmp [b][h][t][d]
// all coalesced in d (consecutive cols -> consecutive d).
struct EpiQKV {
    u16 *Q, *Kt, *Vt;
    __device__ void operator()(int z, int row, int col, float val) const {
        int b = row >> 9, pos = row & 511;
        int sec = col >> 10, cc = col & 1023;
        int head = cc >> 6, d = cc & 63;
        if (sec == 0) {
            if (pos >= 256)
                Q[(long)((head * 8 + b) * 256 + (pos - 256)) * 64 + d] = f2b(val * 0.125f);
        } else if (sec == 1) {
            Kt[(long)((b * 16 + head) * 512 + pos) * 64 + d] = f2b(val);
        } else {
            Vt[(long)((b * 16 + head) * 512 + pos) * 64 + d] = f2b(val);
        }
    }
};

struct EpiStoreBf {
    u16* C; long ldc; long strideZ;
    __device__ void operator()(int z, int row, int col, float val) const {
        C[(long)z * strideZ + (long)row * ldc + col] = f2b(val);
    }
};

struct EpiStoreF32 {
    float* C; long ldc;
    __device__ void operator()(int z, int row, int col, float val) const {
        C[(long)row * ldc + col] = val;
    }
};

// ---------------- 64x64-tile GEMM (C = A @ B^T), LDS-staged ----------------
// AF32: A is float32, converted during staging. ADDA: add 0.125*av[k] to A frags.

template <typename Epi, bool AF32 = false, bool ADDA = false>
__global__ __launch_bounds__(256) void gemm_bt(const void* __restrict__ Av, int lda, long strideAz,
                                               const u16* __restrict__ B, int ldb, long strideBz,
                                               int K, Epi epi, const float* __restrict__ av) {
    constexpr int LDT = 56;
    __shared__ alignas(16) u16 As[64 * LDT];
    __shared__ alignas(16) u16 Bs[64 * LDT];
    int n0 = blockIdx.x * 64, m0 = blockIdx.y * 64, z = blockIdx.z;
    const u16* Bb = B + (long)z * strideBz + (long)n0 * ldb;
    int tid = threadIdx.x;
    int wave = tid >> 6, lane = tid & 63;
    int wm = wave >> 1, wn = wave & 1;
    int lrow = lane & 15, lquad = lane >> 4;
    int srow = tid >> 2, scol = (tid & 3) * 8;
    f32x4 acc[2][2] = {};
    for (int k0 = 0; k0 < K; k0 += 32) {
        if constexpr (AF32) {
            const float* Af = (const float*)Av + (long)z * strideAz + (long)m0 * lda;
            const float* src = Af + (long)srow * lda + k0 + scol;
            float4 f0 = *(const float4*)src;
            float4 f1 = *(const float4*)(src + 4);
            bf16x8 vv;
            vv[0] = (short)f2b(f0.x); vv[1] = (short)f2b(f0.y);
            vv[2] = (short)f2b(f0.z); vv[3] = (short)f2b(f0.w);
            vv[4] = (short)f2b(f1.x); vv[5] = (short)f2b(f1.y);
            vv[6] = (short)f2b(f1.z); vv[7] = (short)f2b(f1.w);
            *(bf16x8*)(As + srow * LDT + scol) = vv;
        } else {
            const u16* Ab = (const u16*)Av + (long)z * strideAz + (long)m0 * lda;
            *(bf16x8*)(As + srow * LDT + scol) = *(const bf16x8*)(Ab + (long)srow * lda + k0 + scol);
        }
        *(bf16x8*)(Bs + srow * LDT + scol) = *(const bf16x8*)(Bb + (long)srow * ldb + k0 + scol);
        __syncthreads();
        bf16x8 af[2], bfr[2];
        #pragma unroll
        for (int mt = 0; mt < 2; ++mt) {
            af[mt] = *(const bf16x8*)(As + (wm * 32 + mt * 16 + lrow) * LDT + lquad * 8);
            if constexpr (ADDA) {
                #pragma unroll
                for (int j = 0; j < 8; ++j)
                    af[mt][j] = (short)f2b(b2f((u16)af[mt][j]) + 0.125f * av[k0 + lquad * 8 + j]);
            }
        }
        #pragma unroll
        for (int nt = 0; nt < 2; ++nt)
            bfr[nt] = *(const bf16x8*)(Bs + (wn * 32 + nt * 16 + lrow) * LDT + lquad * 8);
        #pragma unroll
        for (int mt = 0; mt < 2; ++mt)
            #pragma unroll
            for (int nt = 0; nt < 2; ++nt)
                acc[mt][nt] = __builtin_amdgcn_mfma_f32_16x16x32_bf16(af[mt], bfr[nt], acc[mt][nt], 0, 0, 0);
        __syncthreads();
    }
    #pragma unroll
    for (int mt = 0; mt < 2; ++mt)
        #pragma unroll
        for (int nt = 0; nt < 2; ++nt)
            #pragma unroll
            for (int r = 0; r < 4; ++r) {
                int row = m0 + wm * 32 + mt * 16 + lquad * 4 + r;
                int col = n0 + wn * 32 + nt * 16 + lrow;
                epi(z, row, col, acc[mt][nt][r]);
            }
}

// ---------------- 128x128-tile GEMM (m97 structure: global_load_lds) ----------------

template <typename Epi>
__global__ __launch_bounds__(256) void gemm128(const u16* __restrict__ A, int lda,
                                               const u16* __restrict__ B, int ldb,
                                               int K, Epi epi) {
    __shared__ alignas(16) u16 As[128 * 32];
    __shared__ alignas(16) u16 Bs[128 * 32];
    int n0 = blockIdx.x * 128, m0 = blockIdx.y * 128;
    int tid = threadIdx.x, wave = tid >> 6, lane = tid & 63;
    int wm = wave >> 1, wn = wave & 1;
    int lrow = lane & 15, lquad = lane >> 4;
    int grow = tid >> 2, gcol = (tid & 3) * 8;
    const u16* Ab = A + (long)m0 * lda;
    const u16* Bb = B + (long)n0 * ldb;
    f32x4 acc[4][4] = {};
    for (int k0 = 0; k0 < K; k0 += 32) {
        gload_lds16(Ab + (long)grow * lda + k0 + gcol,        As + grow * 32 + gcol);
        gload_lds16(Ab + (long)(grow + 64) * lda + k0 + gcol, As + (grow + 64) * 32 + gcol);
        gload_lds16(Bb + (long)grow * ldb + k0 + gcol,        Bs + grow * 32 + gcol);
        gload_lds16(Bb + (long)(grow + 64) * ldb + k0 + gcol, Bs + (grow + 64) * 32 + gcol);
        __syncthreads();
        bf16x8 af[4], bfr[4];
        #pragma unroll
        for (int mt = 0; mt < 4; ++mt)
            af[mt] = *(const bf16x8*)(As + (wm * 64 + mt * 16 + lrow) * 32 + lquad * 8);
        #pragma unroll
        for (int nt = 0; nt < 4; ++nt)
            bfr[nt] = *(const bf16x8*)(Bs + (wn * 64 + nt * 16 + lrow) * 32 + lquad * 8);
        #pragma unroll
        for (int mt = 0; mt < 4; ++mt)
            #pragma unroll
            for (int nt = 0; nt < 4; ++nt)
                acc[mt][nt] = __builtin_amdgcn_mfma_f32_16x16x32_bf16(af[mt], bfr[nt], acc[mt][nt], 0, 0, 0);
        __syncthreads();
    }
    #pragma unroll
    for (int mt = 0; mt < 4; ++mt)
        #pragma unroll
        for (int nt = 0; nt < 4; ++nt)
            #pragma unroll
            for (int r = 0; r < 4; ++r) {
                int row = m0 + wm * 64 + mt * 16 + lquad * 4 + r;
                int col = n0 + wn * 64 + nt * 16 + lrow;
                epi(0, row, col, acc[mt][nt][r]);
            }
}

// ---------------- fused attention (register softmax) ----------------
// Q is pre-scaled by 0.125; u folded in here (A-fragment k index = d).
__global__ __launch_bounds__(256) void attn_kernel(const u16* __restrict__ Qs,
                                                   const u16* __restrict__ Kt,
                                                   const u16* __restrict__ VT,
                                                   const u16* __restrict__ QR,
                                                   const float* __restrict__ uvec,
                                                   u16* __restrict__ attnOut) {
    constexpr int SLDB = 520;
    __shared__ alignas(16) u16 Sb[16 * SLDB];
    __shared__ float red[2][4][16];
    int id = blockIdx.x;
    int bh = id & 127, it = id >> 7;
    int b = bh >> 4, h = bh & 15;
    int i0 = it * 16;
    int tid = threadIdx.x, wave = tid >> 6, lane = tid & 63;
    int lrow = lane & 15, lquad = lane >> 4;

    const u16* qbase = Qs + (long)((h * 8 + b) * 256 + i0 + lrow) * 64;
    bf16x8 aq0 = *(const bf16x8*)(qbase + lquad * 8);
    bf16x8 aq1 = *(const bf16x8*)(qbase + 32 + lquad * 8);
    #pragma unroll
    for (int j = 0; j < 8; ++j) {
        aq0[j] = (short)f2b(b2f((u16)aq0[j]) + 0.125f * uvec[lquad * 8 + j]);
        aq1[j] = (short)f2b(b2f((u16)aq1[j]) + 0.125f * uvec[32 + lquad * 8 + j]);
    }

    const u16* kbase = Kt + (long)(bh * 512) * 64;
    const u16* qrbase = QR + ((long)h * 2048 + b * 256) * 320;

    // ---- QK^T into registers ----
    f32x4 acc[8];
    #pragma unroll
    for (int jt = 0; jt < 8; ++jt) {
        const u16* kp = kbase + (long)(wave * 128 + jt * 16 + lrow) * 64;
        bf16x8 bk0 = *(const bf16x8*)(kp + lquad * 8);
        bf16x8 bk1 = *(const bf16x8*)(kp + 32 + lquad * 8);
        f32x4 a = {0.f, 0.f, 0.f, 0.f};
        a = __builtin_amdgcn_mfma_f32_16x16x32_bf16(aq0, bk0, a, 0, 0, 0);
        a = __builtin_amdgcn_mfma_f32_16x16x32_bf16(aq1, bk1, a, 0, 0, 0);
        acc[jt] = a;
    }

    // ---- add rel-term, mask; per-lane row max (everything pre-scaled) ----
    float m4[4] = {-1e30f, -1e30f, -1e30f, -1e30f};
    #pragma unroll
    for (int jt = 0; jt < 8; ++jt) {
        int j = wave * 128 + jt * 16 + lrow;
        #pragma unroll
        for (int r = 0; r < 4; ++r) {
            int iloc = lquad * 4 + r;
            int i = i0 + iloc;
            int s = (j - i - 256) & 1023;
            int sc = (s >= 768) ? (s - 768) : 256;
            bool ok = (j >= 256) ? ((j - 256) <= i) : (j >= i);
            float val = ok ? acc[jt][r] + b2f(qrbase[(long)(i0 + iloc) * 320 + sc]) : -1e30f;
            acc[jt][r] = val;
            m4[r] = fmaxf(m4[r], val);
        }
    }
    #pragma unroll
    for (int r = 0; r < 4; ++r)
        #pragma unroll
        for (int off = 1; off < 16; off <<= 1)
            m4[r] = fmaxf(m4[r], __shfl_xor(m4[r], off));
    if (lrow == 0)
        #pragma unroll
        for (int r = 0; r < 4; ++r) red[0][wave][lquad * 4 + r] = m4[r];
    __syncthreads();

    float gmax[4];
    #pragma unroll
    for (int r = 0; r < 4; ++r) {
        int row = lquad * 4 + r;
        gmax[r] = fmaxf(fmaxf(red[0][0][row], red[0][1][row]),
                        fmaxf(red[0][2][row], red[0][3][row]));
    }

    // ---- exp, write bf16 probs, per-lane row sums ----
    float s4[4] = {0.f, 0.f, 0.f, 0.f};
    #pragma unroll
    for (int jt = 0; jt < 8; ++jt) {
        int j = wave * 128 + jt * 16 + lrow;
        #pragma unroll
        for (int r = 0; r < 4; ++r) {
            float p = __expf(acc[jt][r] - gmax[r]);
            s4[r] += p;
            Sb[(lquad * 4 + r) * SLDB + j] = f2b(p);
        }
    }
    #pragma unroll
    for (int r = 0; r < 4; ++r)
        #pragma unroll
        for (int off = 1; off < 16; off <<= 1)
            s4[r] += __shfl_xor(s4[r], off);
    if (lrow == 0)
        #pragma unroll
        for (int r = 0; r < 4; ++r) red[1][wave][lquad * 4 + r] = s4[r];
    __syncthreads();

    // ---- PV ----
    const u16* vbase = VT + (long)(bh * 64 + wave * 16 + lrow) * 512;
    const u16* sbrow = Sb + lrow * SLDB;
    f32x4 oacc = {0.f, 0.f, 0.f, 0.f};
    #pragma unroll
    for (int ks = 0; ks < 16; ++ks) {
        bf16x8 ap = *(const bf16x8*)(sbrow + ks * 32 + lquad * 8);
        bf16x8 bp = *(const bf16x8*)(vbase + ks * 32 + lquad * 8);
        oacc = __builtin_amdgcn_mfma_f32_16x16x32_bf16(ap, bp, oacc, 0, 0, 0);
    }
    #pragma unroll
    for (int r = 0; r < 4; ++r) {
        int row = lquad * 4 + r;
        float inv = 1.0f / (red[1][0][row] + red[1][1][row] + red[1][2][row] + red[1][3][row]);
        attnOut[(long)(b * 256 + i0 + row) * 1024 + h * 64 + wave * 16 + lrow] = f2b(oacc[r] * inv);
    }
}

// ---------------- launch ----------------

extern "C" void kernel_launch(void* const* d_in, const int* in_sizes, int n_in,
                              void* d_out, int out_size, void* d_ws, size_t ws_size,
                              hipStream_t stream) {
    (void)in_sizes; (void)n_in; (void)out_size; (void)ws_size;
    const float* x    = (const float*)d_in[0];
    const float* h    = (const float*)d_in[1];
    const float* Wqkv = (const float*)d_in[2];
    const float* Wkr  = (const float*)d_in[3];
    const float* R    = (const float*)d_in[4];
    const float* u    = (const float*)d_in[5];
    const float* v    = (const float*)d_in[6];
    const float* Wout = (const float*)d_in[7];
    float* out = (float*)d_out;

    char* ws = (char*)d_ws;
    size_t off = 0;
    auto alloc = [&](size_t bytes) -> void* {
        void* p = ws + off;
        off = (off + bytes + 255) & ~(size_t)255;
        return p;
    };
    u16* catBF  = (u16*)alloc(4096L * 1024 * 2);   // [b*512][1024]
    u16* WqkvT  = (u16*)alloc(3072L * 1024 * 2);
    u16* WkrT   = (u16*)alloc(1024L * 1024 * 2);
    u16* WoutT  = (u16*)alloc(1024L * 1024 * 2);
    u16* RW     = (u16*)alloc(1024L * 1024 * 2);   // [s][1024]
    u16* RWg    = (u16*)alloc(320L * 1024 * 2);    // live shift rows
    u16* Q      = (u16*)alloc(16L * 8 * 256 * 64 * 2);   // [h][b][i][d], 0.125*q
    u16* Kt     = (u16*)alloc(8L * 16 * 512 * 64 * 2);   // [b][h][t][d]
    u16* Vtmp   = (u16*)alloc(8L * 16 * 512 * 64 * 2);   // [b][h][t][d]
    u16* VT     = (u16*)alloc(8L * 16 * 64 * 512 * 2);   // [b][h][d][t]
    u16* QR     = (u16*)alloc(16L * 2048 * 320 * 2);     // [h][b*256+i][sc]
    u16* attnO  = (u16*)alloc(2048L * 1024 * 2);   // [b*256+i][h*64+d]

    cast_cat<<<16384, 256, 0, stream>>>(x, h, catBF);
    transpose_cast<<<dim3(96, 32), 256, 0, stream>>>(Wqkv, WqkvT, 1024, 3072);
    transpose_cast<<<dim3(32, 32), 256, 0, stream>>>(Wkr, WkrT, 1024, 1024);
    transpose_cast<<<dim3(32, 32), 256, 0, stream>>>(Wout, WoutT, 1024, 1024);

    // RW = R @ Wkr  (1024x1024x1024), A read as f32 directly
    gemm_bt<EpiStoreBf, true><<<dim3(16, 16, 1), 256, 0, stream>>>(
        (const void*)R, 1024, 0L, WkrT, 1024, 0L, 1024, EpiStoreBf{RW, 1024, 0}, nullptr);
    gather_rwg<<<1280, 256, 0, stream>>>(RW, RWg);
    // QKV = cat @ Wqkv  (4096x3072x1024), coalesced scatter epilogue
    gemm128<<<dim3(24, 32), 256, 0, stream>>>(catBF, 1024, WqkvT, 1024, 1024,
                                              EpiQKV{Q, Kt, Vtmp});
    transpose_v<<<dim3(16, 2, 128), 256, 0, stream>>>(Vtmp, VT);
    // QR[h] = (0.125*(q+v))[h] @ RWg[:, h*64:+64]^T  (M=2048, N=320, K=64), v folded
    gemm_bt<EpiStoreBf, false, true><<<dim3(5, 32, 16), 256, 0, stream>>>(
        (const void*)Q, 64, 2048L * 64, RWg, 1024, 64L, 64,
        EpiStoreBf{QR, 320, 2048L * 320}, v);
    attn_kernel<<<2048, 256, 0, stream>>>(Q, Kt, VT, QR, u, attnO);
    // out = attnOut @ Wout  (2048x1024x1024)
    gemm_bt<EpiStoreF32><<<dim3(16, 32, 1), 256, 0, stream>>>(
        (const void*)attnO, 1024, 0L, WoutT, 1024, 0L, 1024, EpiStoreF32{out, 1024}, nullptr);
}

// Round 5
// 233.625 us; speedup vs baseline: 1.2508x; 1.0708x over previous
//
#include <hip/hip_runtime.h>
#include <hip/hip_bf16.h>
#include <math.h>

typedef unsigned short u16;
typedef short bf16x8 __attribute__((ext_vector_type(8)));
typedef float f32x4 __attribute__((ext_vector_type(4)));

__device__ __forceinline__ u16 f2b(float f) {
    __hip_bfloat16 h = __float2bfloat16(f);
    return *reinterpret_cast<u16*>(&h);
}
__device__ __forceinline__ float b2f(u16 v) {
    __hip_bfloat16 h;
    *reinterpret_cast<u16*>(&h) = v;
    return __bfloat162float(h);
}

__device__ __forceinline__ void gload_lds16(const void* g, void* l) {
    __builtin_amdgcn_global_load_lds(
        (const __attribute__((address_space(1))) void*)g,
        (__attribute__((address_space(3))) void*)l, 16, 0, 0);
}

// ---------------- cast / transpose kernels ----------------

// cat = concat([h, x], axis=1) -> bf16 [b*512][1024], 8 elems/thread
__global__ __launch_bounds__(256) void cast_cat(const float* __restrict__ x,
                                                const float* __restrict__ h,
                                                u16* __restrict__ catBF) {
    int idx = (blockIdx.x * 256 + threadIdx.x) * 8;   // < 4096*1024
    int c = idx & 1023, r = idx >> 10;
    int b = r >> 9, pos = r & 511;
    const float* src = (pos < 256) ? h + ((long)(b * 256 + pos) * 1024 + c)
                                   : x + ((long)(b * 256 + pos - 256) * 1024 + c);
    float4 f0 = *(const float4*)src;
    float4 f1 = *(const float4*)(src + 4);
    bf16x8 vv;
    vv[0] = (short)f2b(f0.x); vv[1] = (short)f2b(f0.y);
    vv[2] = (short)f2b(f0.z); vv[3] = (short)f2b(f0.w);
    vv[4] = (short)f2b(f1.x); vv[5] = (short)f2b(f1.y);
    vv[6] = (short)f2b(f1.z); vv[7] = (short)f2b(f1.w);
    *(bf16x8*)(catBF + idx) = vv;
}

// W [K][N] f32 -> WT [N][K] bf16, vectorized ushort4 stores
__global__ __launch_bounds__(256) void transpose_cast(const float* __restrict__ W,
                                                      u16* __restrict__ WT,
                                                      int K, int N) {
    __shared__ float tile[32][33];
    int nb = blockIdx.x * 32, kb = blockIdx.y * 32;
    int tx = threadIdx.x & 31, ty = threadIdx.x >> 5;
    #pragma unroll
    for (int i = 0; i < 32; i += 8)
        tile[ty + i][tx] = W[(long)(kb + ty + i) * N + nb + tx];
    __syncthreads();
    int row = threadIdx.x >> 3;        // output n-row 0..31
    int c4 = (threadIdx.x & 7) * 4;    // k offset
    ushort4 o;
    o.x = f2b(tile[c4 + 0][row]);
    o.y = f2b(tile[c4 + 1][row]);
    o.z = f2b(tile[c4 + 2][row]);
    o.w = f2b(tile[c4 + 3][row]);
    *(ushort4*)(WT + (long)(nb + row) * K + kb + c4) = o;
}

// Vtmp [bh][t][d] -> VT [bh][d][t]
__global__ __launch_bounds__(256) void transpose_v(const u16* __restrict__ Vtmp,
                                                   u16* __restrict__ VT) {
    __shared__ u16 tile[32][34];
    int t0 = blockIdx.x * 32, d0 = blockIdx.y * 32, bh = blockIdx.z;
    int tx = threadIdx.x & 31, ty = threadIdx.x >> 5;
    const u16* src = Vtmp + (long)bh * 512 * 64;
    #pragma unroll
    for (int i = 0; i < 32; i += 8)
        tile[ty + i][tx] = src[(long)(t0 + ty + i) * 64 + d0 + tx];
    __syncthreads();
    u16* dst = VT + (long)bh * 64 * 512;
    #pragma unroll
    for (int i = 0; i < 32; i += 8)
        dst[(long)(d0 + ty + i) * 512 + t0 + tx] = tile[tx][ty + i];
}

// ---------------- epilogues ----------------

struct EpiQKV {
    u16 *Q, *Kt, *Vt;
    __device__ void operator()(int z, int row, int col, float val) const {
        int b = row >> 9, pos = row & 511;
        int sec = col >> 10, cc = col & 1023;
        int head = cc >> 6, d = cc & 63;
        if (sec == 0) {
            if (pos >= 256)
                Q[(long)((head * 8 + b) * 256 + (pos - 256)) * 64 + d] = f2b(val * 0.125f);
        } else if (sec == 1) {
            Kt[(long)((b * 16 + head) * 512 + pos) * 64 + d] = f2b(val);
        } else {
            Vt[(long)((b * 16 + head) * 512 + pos) * 64 + d] = f2b(val);
        }
    }
};

struct EpiStoreBf {
    u16* C; long ldc; long strideZ;
    __device__ void operator()(int z, int row, int col, float val) const {
        C[(long)z * strideZ + (long)row * ldc + col] = f2b(val);
    }
};

struct EpiStoreF32 {
    float* C; long ldc;
    __device__ void operator()(int z, int row, int col, float val) const {
        C[(long)row * ldc + col] = val;
    }
};

// ---------------- 64x64-tile GEMM (C = A @ B^T), LDS-staged ----------------
// AF32: A is f32, converted during staging. ADDA: add 0.125*av[k] to A frags.
// ROWMAP: A row remap r -> (r<256 ? 768+r : 0)  (live rel-shift rows of R).

template <typename Epi, bool AF32 = false, bool ADDA = false, bool ROWMAP = false>
__global__ __launch_bounds__(256) void gemm_bt(const void* __restrict__ Av, int lda, long strideAz,
                                               const u16* __restrict__ B, int ldb, long strideBz,
                                               int K, Epi epi, const float* __restrict__ av) {
    constexpr int LDT = 56;
    __shared__ alignas(16) u16 As[64 * LDT];
    __shared__ alignas(16) u16 Bs[64 * LDT];
    int n0 = blockIdx.x * 64, m0 = blockIdx.y * 64, z = blockIdx.z;
    const u16* Bb = B + (long)z * strideBz + (long)n0 * ldb;
    int tid = threadIdx.x;
    int wave = tid >> 6, lane = tid & 63;
    int wm = wave >> 1, wn = wave & 1;
    int lrow = lane & 15, lquad = lane >> 4;
    int srow = tid >> 2, scol = (tid & 3) * 8;
    f32x4 acc[2][2] = {};
    for (int k0 = 0; k0 < K; k0 += 32) {
        if constexpr (AF32) {
            long arow = m0 + srow;
            if constexpr (ROWMAP) arow = (arow < 256) ? 768 + arow : 0;
            const float* src = (const float*)Av + (long)z * strideAz + arow * lda + k0 + scol;
            float4 f0 = *(const float4*)src;
            float4 f1 = *(const float4*)(src + 4);
            bf16x8 vv;
            vv[0] = (short)f2b(f0.x); vv[1] = (short)f2b(f0.y);
            vv[2] = (short)f2b(f0.z); vv[3] = (short)f2b(f0.w);
            vv[4] = (short)f2b(f1.x); vv[5] = (short)f2b(f1.y);
            vv[6] = (short)f2b(f1.z); vv[7] = (short)f2b(f1.w);
            *(bf16x8*)(As + srow * LDT + scol) = vv;
        } else {
            const u16* Ab = (const u16*)Av + (long)z * strideAz + (long)m0 * lda;
            *(bf16x8*)(As + srow * LDT + scol) = *(const bf16x8*)(Ab + (long)srow * lda + k0 + scol);
        }
        *(bf16x8*)(Bs + srow * LDT + scol) = *(const bf16x8*)(Bb + (long)srow * ldb + k0 + scol);
        __syncthreads();
        bf16x8 af[2], bfr[2];
        #pragma unroll
        for (int mt = 0; mt < 2; ++mt) {
            af[mt] = *(const bf16x8*)(As + (wm * 32 + mt * 16 + lrow) * LDT + lquad * 8);
            if constexpr (ADDA) {
                #pragma unroll
                for (int j = 0; j < 8; ++j)
                    af[mt][j] = (short)f2b(b2f((u16)af[mt][j]) + 0.125f * av[k0 + lquad * 8 + j]);
            }
        }
        #pragma unroll
        for (int nt = 0; nt < 2; ++nt)
            bfr[nt] = *(const bf16x8*)(Bs + (wn * 32 + nt * 16 + lrow) * LDT + lquad * 8);
        #pragma unroll
        for (int mt = 0; mt < 2; ++mt)
            #pragma unroll
            for (int nt = 0; nt < 2; ++nt)
                acc[mt][nt] = __builtin_amdgcn_mfma_f32_16x16x32_bf16(af[mt], bfr[nt], acc[mt][nt], 0, 0, 0);
        __syncthreads();
    }
    #pragma unroll
    for (int mt = 0; mt < 2; ++mt)
        #pragma unroll
        for (int nt = 0; nt < 2; ++nt)
            #pragma unroll
            for (int r = 0; r < 4; ++r) {
                int row = m0 + wm * 32 + mt * 16 + lquad * 4 + r;
                int col = n0 + wn * 32 + nt * 16 + lrow;
                epi(z, row, col, acc[mt][nt][r]);
            }
}

// ---------------- 128x128-tile GEMM (m97 structure) ----------------

template <typename Epi>
__global__ __launch_bounds__(256) void gemm128(const u16* __restrict__ A, int lda,
                                               const u16* __restrict__ B, int ldb,
                                               int K, Epi epi) {
    __shared__ alignas(16) u16 As[128 * 32];
    __shared__ alignas(16) u16 Bs[128 * 32];
    int n0 = blockIdx.x * 128, m0 = blockIdx.y * 128;
    int tid = threadIdx.x, wave = tid >> 6, lane = tid & 63;
    int wm = wave >> 1, wn = wave & 1;
    int lrow = lane & 15, lquad = lane >> 4;
    int grow = tid >> 2, gcol = (tid & 3) * 8;
    const u16* Ab = A + (long)m0 * lda;
    const u16* Bb = B + (long)n0 * ldb;
    f32x4 acc[4][4] = {};
    for (int k0 = 0; k0 < K; k0 += 32) {
        gload_lds16(Ab + (long)grow * lda + k0 + gcol,        As + grow * 32 + gcol);
        gload_lds16(Ab + (long)(grow + 64) * lda + k0 + gcol, As + (grow + 64) * 32 + gcol);
        gload_lds16(Bb + (long)grow * ldb + k0 + gcol,        Bs + grow * 32 + gcol);
        gload_lds16(Bb + (long)(grow + 64) * ldb + k0 + gcol, Bs + (grow + 64) * 32 + gcol);
        __syncthreads();
        bf16x8 af[4], bfr[4];
        #pragma unroll
        for (int mt = 0; mt < 4; ++mt)
            af[mt] = *(const bf16x8*)(As + (wm * 64 + mt * 16 + lrow) * 32 + lquad * 8);
        #pragma unroll
        for (int nt = 0; nt < 4; ++nt)
            bfr[nt] = *(const bf16x8*)(Bs + (wn * 64 + nt * 16 + lrow) * 32 + lquad * 8);
        #pragma unroll
        for (int mt = 0; mt < 4; ++mt)
            #pragma unroll
            for (int nt = 0; nt < 4; ++nt)
                acc[mt][nt] = __builtin_amdgcn_mfma_f32_16x16x32_bf16(af[mt], bfr[nt], acc[mt][nt], 0, 0, 0);
        __syncthreads();
    }
    #pragma unroll
    for (int mt = 0; mt < 4; ++mt)
        #pragma unroll
        for (int nt = 0; nt < 4; ++nt)
            #pragma unroll
            for (int r = 0; r < 4; ++r) {
                int row = m0 + wm * 64 + mt * 16 + lquad * 4 + r;
                int col = n0 + wn * 64 + nt * 16 + lrow;
                epi(0, row, col, acc[mt][nt][r]);
            }
}

// ---------------- fused attention ----------------
// launch_bounds(256,4): ~128 VGPRs for load ILP. QR slice staged in LDS.
__global__ __launch_bounds__(256, 4) void attn_kernel(const u16* __restrict__ Qs,
                                                      const u16* __restrict__ Kt,
                                                      const u16* __restrict__ VT,
                                                      const u16* __restrict__ QR,
                                                      const float* __restrict__ uvec,
                                                      u16* __restrict__ attnOut) {
    constexpr int SLDB = 520;
    constexpr int QLD = 344;   // u16 stride: quad groups 2-way alias only
    __shared__ alignas(16) u16 Sb[16 * SLDB];
    __shared__ alignas(16) u16 QRs[16 * QLD];
    __shared__ float red[2][4][16];
    int id = blockIdx.x;
    int bh = id & 127, it = id >> 7;
    int b = bh >> 4, h = bh & 15;
    int i0 = it * 16;
    int tid = threadIdx.x, wave = tid >> 6, lane = tid & 63;
    int lrow = lane & 15, lquad = lane >> 4;

    // ---- stage QR slice (16 rows x 320 u16) into LDS, b128 coalesced ----
    const u16* qrg = QR + ((long)h * 2048 + b * 256 + i0) * 320;
    for (int idx = tid; idx < 640; idx += 256) {
        int row = idx / 40, c = idx - row * 40;
        *(bf16x8*)(QRs + row * QLD + c * 8) = *(const bf16x8*)(qrg + row * 320 + c * 8);
    }

    // ---- Q fragments + u fold (Q pre-scaled by 0.125) ----
    const u16* qbase = Qs + (long)((h * 8 + b) * 256 + i0 + lrow) * 64;
    bf16x8 aq0 = *(const bf16x8*)(qbase + lquad * 8);
    bf16x8 aq1 = *(const bf16x8*)(qbase + 32 + lquad * 8);
    #pragma unroll
    for (int j = 0; j < 8; ++j) {
        aq0[j] = (short)f2b(b2f((u16)aq0[j]) + 0.125f * uvec[lquad * 8 + j]);
        aq1[j] = (short)f2b(b2f((u16)aq1[j]) + 0.125f * uvec[32 + lquad * 8 + j]);
    }

    // ---- QK^T, K fragments preloaded 4 j-tiles at a time ----
    const u16* kbase = Kt + (long)(bh * 512) * 64;
    f32x4 acc[8];
    #pragma unroll
    for (int half = 0; half < 2; ++half) {
        bf16x8 bk0[4], bk1[4];
        #pragma unroll
        for (int t = 0; t < 4; ++t) {
            const u16* kp = kbase + (long)(wave * 128 + (half * 4 + t) * 16 + lrow) * 64;
            bk0[t] = *(const bf16x8*)(kp + lquad * 8);
            bk1[t] = *(const bf16x8*)(kp + 32 + lquad * 8);
        }
        #pragma unroll
        for (int t = 0; t < 4; ++t) {
            f32x4 a = {0.f, 0.f, 0.f, 0.f};
            a = __builtin_amdgcn_mfma_f32_16x16x32_bf16(aq0, bk0[t], a, 0, 0, 0);
            a = __builtin_amdgcn_mfma_f32_16x16x32_bf16(aq1, bk1[t], a, 0, 0, 0);
            acc[half * 4 + t] = a;
        }
    }
    __syncthreads();   // QRs staged

    // ---- combine rel-term (from LDS), mask; per-lane row max ----
    float m4[4] = {-1e30f, -1e30f, -1e30f, -1e30f};
    #pragma unroll
    for (int jt = 0; jt < 8; ++jt) {
        int j = wave * 128 + jt * 16 + lrow;
        #pragma unroll
        for (int r = 0; r < 4; ++r) {
            int iloc = lquad * 4 + r;
            int i = i0 + iloc;
            int s = (j - i - 256) & 1023;
            int sc = (s >= 768) ? (s - 768) : 256;
            bool ok = (j >= 256) ? ((j - 256) <= i) : (j >= i);
            float val = ok ? acc[jt][r] + b2f(QRs[iloc * QLD + sc]) : -1e30f;
            acc[jt][r] = val;
            m4[r] = fmaxf(m4[r], val);
        }
    }
    #pragma unroll
    for (int r = 0; r < 4; ++r)
        #pragma unroll
        for (int off = 1; off < 16; off <<= 1)
            m4[r] = fmaxf(m4[r], __shfl_xor(m4[r], off));
    if (lrow == 0)
        #pragma unroll
        for (int r = 0; r < 4; ++r) red[0][wave][lquad * 4 + r] = m4[r];
    __syncthreads();

    float gmax[4];
    #pragma unroll
    for (int r = 0; r < 4; ++r) {
        int row = lquad * 4 + r;
        gmax[r] = fmaxf(fmaxf(red[0][0][row], red[0][1][row]),
                        fmaxf(red[0][2][row], red[0][3][row]));
    }

    // ---- exp, write bf16 probs, per-lane row sums ----
    float s4[4] = {0.f, 0.f, 0.f, 0.f};
    #pragma unroll
    for (int jt = 0; jt < 8; ++jt) {
        int j = wave * 128 + jt * 16 + lrow;
        #pragma unroll
        for (int r = 0; r < 4; ++r) {
            float p = __expf(acc[jt][r] - gmax[r]);
            s4[r] += p;
            Sb[(lquad * 4 + r) * SLDB + j] = f2b(p);
        }
    }
    #pragma unroll
    for (int r = 0; r < 4; ++r)
        #pragma unroll
        for (int off = 1; off < 16; off <<= 1)
            s4[r] += __shfl_xor(s4[r], off);
    if (lrow == 0)
        #pragma unroll
        for (int r = 0; r < 4; ++r) red[1][wave][lquad * 4 + r] = s4[r];
    __syncthreads();

    // ---- PV, V fragments preloaded 8 at a time ----
    const u16* vbase = VT + (long)(bh * 64 + wave * 16 + lrow) * 512;
    const u16* sbrow = Sb + lrow * SLDB;
    f32x4 oacc = {0.f, 0.f, 0.f, 0.f};
    #pragma unroll
    for (int half = 0; half < 2; ++half) {
        bf16x8 vp[8];
        #pragma unroll
        for (int t = 0; t < 8; ++t)
            vp[t] = *(const bf16x8*)(vbase + (half * 8 + t) * 32 + lquad * 8);
        #pragma unroll
        for (int t = 0; t < 8; ++t) {
            bf16x8 ap = *(const bf16x8*)(sbrow + (half * 8 + t) * 32 + lquad * 8);
            oacc = __builtin_amdgcn_mfma_f32_16x16x32_bf16(ap, vp[t], oacc, 0, 0, 0);
        }
    }
    #pragma unroll
    for (int r = 0; r < 4; ++r) {
        int row = lquad * 4 + r;
        float inv = 1.0f / (red[1][0][row] + red[1][1][row] + red[1][2][row] + red[1][3][row]);
        attnOut[(long)(b * 256 + i0 + row) * 1024 + h * 64 + wave * 16 + lrow] = f2b(oacc[r] * inv);
    }
}

// ---------------- launch ----------------

extern "C" void kernel_launch(void* const* d_in, const int* in_sizes, int n_in,
                              void* d_out, int out_size, void* d_ws, size_t ws_size,
                              hipStream_t stream) {
    (void)in_sizes; (void)n_in; (void)out_size; (void)ws_size;
    const float* x    = (const float*)d_in[0];
    const float* h    = (const float*)d_in[1];
    const float* Wqkv = (const float*)d_in[2];
    const float* Wkr  = (const float*)d_in[3];
    const float* R    = (const float*)d_in[4];
    const float* u    = (const float*)d_in[5];
    const float* v    = (const float*)d_in[6];
    const float* Wout = (const float*)d_in[7];
    float* out = (float*)d_out;

    char* ws = (char*)d_ws;
    size_t off = 0;
    auto alloc = [&](size_t bytes) -> void* {
        void* p = ws + off;
        off = (off + bytes + 255) & ~(size_t)255;
        return p;
    };
    u16* catBF  = (u16*)alloc(4096L * 1024 * 2);   // [b*512][1024]
    u16* WqkvT  = (u16*)alloc(3072L * 1024 * 2);
    u16* WkrT   = (u16*)alloc(1024L * 1024 * 2);
    u16* WoutT  = (u16*)alloc(1024L * 1024 * 2);
    u16* RWg    = (u16*)alloc(320L * 1024 * 2);    // live shift rows of R@Wkr
    u16* Q      = (u16*)alloc(16L * 8 * 256 * 64 * 2);   // [h][b][i][d], 0.125*q
    u16* Kt     = (u16*)alloc(8L * 16 * 512 * 64 * 2);   // [b][h][t][d]
    u16* Vtmp   = (u16*)alloc(8L * 16 * 512 * 64 * 2);   // [b][h][t][d]
    u16* VT     = (u16*)alloc(8L * 16 * 64 * 512 * 2);   // [b][h][d][t]
    u16* QR     = (u16*)alloc(16L * 2048 * 320 * 2);     // [h][b*256+i][sc]
    u16* attnO  = (u16*)alloc(2048L * 1024 * 2);   // [b*256+i][h*64+d]

    cast_cat<<<2048, 256, 0, stream>>>(x, h, catBF);
    transpose_cast<<<dim3(96, 32), 256, 0, stream>>>(Wqkv, WqkvT, 1024, 3072);
    transpose_cast<<<dim3(32, 32), 256, 0, stream>>>(Wkr, WkrT, 1024, 1024);
    transpose_cast<<<dim3(32, 32), 256, 0, stream>>>(Wout, WoutT, 1024, 1024);

    // RWg = (live rows of R) @ Wkr  (M=320, K=1024), f32 A + row remap
    gemm_bt<EpiStoreBf, true, false, true><<<dim3(16, 5, 1), 256, 0, stream>>>(
        (const void*)R, 1024, 0L, WkrT, 1024, 0L, 1024, EpiStoreBf{RWg, 1024, 0}, nullptr);
    // QKV = cat @ Wqkv  (4096x3072x1024)
    gemm128<<<dim3(24, 32), 256, 0, stream>>>(catBF, 1024, WqkvT, 1024, 1024,
                                              EpiQKV{Q, Kt, Vtmp});
    transpose_v<<<dim3(16, 2, 128), 256, 0, stream>>>(Vtmp, VT);
    // QR[h] = (0.125*(q+v))[h] @ RWg[:, h*64:+64]^T  (M=2048, N=320, K=64)
    gemm_bt<EpiStoreBf, false, true><<<dim3(5, 32, 16), 256, 0, stream>>>(
        (const void*)Q, 64, 2048L * 64, RWg, 1024, 64L, 64,
        EpiStoreBf{QR, 320, 2048L * 320}, v);
    attn_kernel<<<2048, 256, 0, stream>>>(Q, Kt, VT, QR, u, attnO);
    // out = attnOut @ Wout  (2048x1024x1024)
    gemm_bt<EpiStoreF32><<<dim3(16, 32, 1), 256, 0, stream>>>(
        (const void*)attnO, 1024, 0L, WoutT, 1024, 0L, 1024, EpiStoreF32{out, 1024}, nullptr);
}

// Round 6
// 230.941 us; speedup vs baseline: 1.2653x; 1.0116x over previous
//
#include <hip/hip_runtime.h>
#include <hip/hip_bf16.h>
#include <math.h>

typedef unsigned short u16;
typedef short bf16x8 __attribute__((ext_vector_type(8)));
typedef float f32x4 __attribute__((ext_vector_type(4)));

__device__ __forceinline__ u16 f2b(float f) {
    __hip_bfloat16 h = __float2bfloat16(f);
    return *reinterpret_cast<u16*>(&h);
}
__device__ __forceinline__ float b2f(u16 v) {
    __hip_bfloat16 h;
    *reinterpret_cast<u16*>(&h) = v;
    return __bfloat162float(h);
}

__device__ __forceinline__ void gload_lds16(const void* g, void* l) {
    __builtin_amdgcn_global_load_lds(
        (const __attribute__((address_space(1))) void*)g,
        (__attribute__((address_space(3))) void*)l, 16, 0, 0);
}

// ---------------- cast / transpose kernels ----------------

// cat = concat([h, x], axis=1) -> bf16 [b*512][1024], 8 elems/thread
__global__ __launch_bounds__(256) void cast_cat(const float* __restrict__ x,
                                                const float* __restrict__ h,
                                                u16* __restrict__ catBF) {
    int idx = (blockIdx.x * 256 + threadIdx.x) * 8;
    int c = idx & 1023, r = idx >> 10;
    int b = r >> 9, pos = r & 511;
    const float* src = (pos < 256) ? h + ((long)(b * 256 + pos) * 1024 + c)
                                   : x + ((long)(b * 256 + pos - 256) * 1024 + c);
    float4 f0 = *(const float4*)src;
    float4 f1 = *(const float4*)(src + 4);
    bf16x8 vv;
    vv[0] = (short)f2b(f0.x); vv[1] = (short)f2b(f0.y);
    vv[2] = (short)f2b(f0.z); vv[3] = (short)f2b(f0.w);
    vv[4] = (short)f2b(f1.x); vv[5] = (short)f2b(f1.y);
    vv[6] = (short)f2b(f1.z); vv[7] = (short)f2b(f1.w);
    *(bf16x8*)(catBF + idx) = vv;
}

// all three weights W [1024][N] f32 -> WT [N][1024] bf16 in one launch
__global__ __launch_bounds__(256) void transpose_cast3(const float* __restrict__ Wqkv, u16* __restrict__ WqkvT,
                                                       const float* __restrict__ Wkr,  u16* __restrict__ WkrT,
                                                       const float* __restrict__ Wout, u16* __restrict__ WoutT) {
    __shared__ float tile[32][33];
    int z = blockIdx.z;
    const float* W; u16* WT; int N;
    if (z == 0)      { W = Wqkv; WT = WqkvT; N = 3072; }
    else if (z == 1) { W = Wkr;  WT = WkrT;  N = 1024; }
    else             { W = Wout; WT = WoutT; N = 1024; }
    int nb = blockIdx.x * 32, kb = blockIdx.y * 32;
    if (nb >= N) return;
    int tx = threadIdx.x & 31, ty = threadIdx.x >> 5;
    #pragma unroll
    for (int i = 0; i < 32; i += 8)
        tile[ty + i][tx] = W[(long)(kb + ty + i) * N + nb + tx];
    __syncthreads();
    int row = threadIdx.x >> 3;
    int c4 = (threadIdx.x & 7) * 4;
    ushort4 o;
    o.x = f2b(tile[c4 + 0][row]);
    o.y = f2b(tile[c4 + 1][row]);
    o.z = f2b(tile[c4 + 2][row]);
    o.w = f2b(tile[c4 + 3][row]);
    *(ushort4*)(WT + (long)(nb + row) * 1024 + kb + c4) = o;
}

// Vtmp [bh][t][d] -> VT [bh][d][t]
__global__ __launch_bounds__(256) void transpose_v(const u16* __restrict__ Vtmp,
                                                   u16* __restrict__ VT) {
    __shared__ u16 tile[32][34];
    int t0 = blockIdx.x * 32, d0 = blockIdx.y * 32, bh = blockIdx.z;
    int tx = threadIdx.x & 31, ty = threadIdx.x >> 5;
    const u16* src = Vtmp + (long)bh * 512 * 64;
    #pragma unroll
    for (int i = 0; i < 32; i += 8)
        tile[ty + i][tx] = src[(long)(t0 + ty + i) * 64 + d0 + tx];
    __syncthreads();
    u16* dst = VT + (long)bh * 64 * 512;
    #pragma unroll
    for (int i = 0; i < 32; i += 8)
        dst[(long)(d0 + ty + i) * 512 + t0 + tx] = tile[tx][ty + i];
}

// ---------------- epilogues ----------------

// Tile epilogue for transposed QKV GEMM: rowp = weight-col base (4 consecutive
// values in vals), colp = pos index. All stores ushort4, coalesced.
struct EpiQKV4 {
    u16 *Q, *Kt, *Vt;
    __device__ void operator()(int rowp, int colp, f32x4 vals) const {
        int b = colp >> 9, pos = colp & 511;
        int sec = rowp >> 10, cc = rowp & 1023;
        int head = cc >> 6, d0 = cc & 63;
        ushort4 o;
        if (sec == 0) {
            if (pos < 256) return;
            o.x = f2b(vals[0] * 0.125f); o.y = f2b(vals[1] * 0.125f);
            o.z = f2b(vals[2] * 0.125f); o.w = f2b(vals[3] * 0.125f);
            *(ushort4*)(Q + (long)((head * 8 + b) * 256 + (pos - 256)) * 64 + d0) = o;
        } else {
            u16* dst = (sec == 1) ? Kt : Vt;
            o.x = f2b(vals[0]); o.y = f2b(vals[1]);
            o.z = f2b(vals[2]); o.w = f2b(vals[3]);
            *(ushort4*)(dst + (long)((b * 16 + head) * 512 + pos) * 64 + d0) = o;
        }
    }
};

struct EpiStoreBf {
    u16* C; long ldc; long strideZ;
    __device__ void operator()(int z, int row, int col, float val) const {
        C[(long)z * strideZ + (long)row * ldc + col] = f2b(val);
    }
};

struct EpiStoreF32 {
    float* C; long ldc;
    __device__ void operator()(int z, int row, int col, float val) const {
        C[(long)row * ldc + col] = val;
    }
};

// ---------------- 64x64-tile GEMM (C = A @ B^T), LDS-staged ----------------

template <typename Epi, bool AF32 = false, bool ADDA = false, bool ROWMAP = false>
__global__ __launch_bounds__(256) void gemm_bt(const void* __restrict__ Av, int lda, long strideAz,
                                               const u16* __restrict__ B, int ldb, long strideBz,
                                               int K, Epi epi, const float* __restrict__ av) {
    constexpr int LDT = 56;
    __shared__ alignas(16) u16 As[64 * LDT];
    __shared__ alignas(16) u16 Bs[64 * LDT];
    int n0 = blockIdx.x * 64, m0 = blockIdx.y * 64, z = blockIdx.z;
    const u16* Bb = B + (long)z * strideBz + (long)n0 * ldb;
    int tid = threadIdx.x;
    int wave = tid >> 6, lane = tid & 63;
    int wm = wave >> 1, wn = wave & 1;
    int lrow = lane & 15, lquad = lane >> 4;
    int srow = tid >> 2, scol = (tid & 3) * 8;
    f32x4 acc[2][2] = {};
    for (int k0 = 0; k0 < K; k0 += 32) {
        if constexpr (AF32) {
            long arow = m0 + srow;
            if constexpr (ROWMAP) arow = (arow < 256) ? 768 + arow : 0;
            const float* src = (const float*)Av + (long)z * strideAz + arow * lda + k0 + scol;
            float4 f0 = *(const float4*)src;
            float4 f1 = *(const float4*)(src + 4);
            bf16x8 vv;
            vv[0] = (short)f2b(f0.x); vv[1] = (short)f2b(f0.y);
            vv[2] = (short)f2b(f0.z); vv[3] = (short)f2b(f0.w);
            vv[4] = (short)f2b(f1.x); vv[5] = (short)f2b(f1.y);
            vv[6] = (short)f2b(f1.z); vv[7] = (short)f2b(f1.w);
            *(bf16x8*)(As + srow * LDT + scol) = vv;
        } else {
            const u16* Ab = (const u16*)Av + (long)z * strideAz + (long)m0 * lda;
            *(bf16x8*)(As + srow * LDT + scol) = *(const bf16x8*)(Ab + (long)srow * lda + k0 + scol);
        }
        *(bf16x8*)(Bs + srow * LDT + scol) = *(const bf16x8*)(Bb + (long)srow * ldb + k0 + scol);
        __syncthreads();
        bf16x8 af[2], bfr[2];
        #pragma unroll
        for (int mt = 0; mt < 2; ++mt) {
            af[mt] = *(const bf16x8*)(As + (wm * 32 + mt * 16 + lrow) * LDT + lquad * 8);
            if constexpr (ADDA) {
                #pragma unroll
                for (int j = 0; j < 8; ++j)
                    af[mt][j] = (short)f2b(b2f((u16)af[mt][j]) + 0.125f * av[k0 + lquad * 8 + j]);
            }
        }
        #pragma unroll
        for (int nt = 0; nt < 2; ++nt)
            bfr[nt] = *(const bf16x8*)(Bs + (wn * 32 + nt * 16 + lrow) * LDT + lquad * 8);
        #pragma unroll
        for (int mt = 0; mt < 2; ++mt)
            #pragma unroll
            for (int nt = 0; nt < 2; ++nt)
                acc[mt][nt] = __builtin_amdgcn_mfma_f32_16x16x32_bf16(af[mt], bfr[nt], acc[mt][nt], 0, 0, 0);
        __syncthreads();
    }
    #pragma unroll
    for (int mt = 0; mt < 2; ++mt)
        #pragma unroll
        for (int nt = 0; nt < 2; ++nt)
            #pragma unroll
            for (int r = 0; r < 4; ++r) {
                int row = m0 + wm * 32 + mt * 16 + lquad * 4 + r;
                int col = n0 + wn * 32 + nt * 16 + lrow;
                epi(z, row, col, acc[mt][nt][r]);
            }
}

// ---------------- 128x128-tile GEMM, tile epilogue (m97 structure) ----------------
// Computes D[m'][n'] = A[m'][k] B[n'][k]^T; epilogue gets one f32x4 per tile:
// rowp = m' base of 4 consecutive values, colp = n'.

template <typename Epi>
__global__ __launch_bounds__(256) void gemm128t(const u16* __restrict__ A, int lda,
                                                const u16* __restrict__ B, int ldb,
                                                int K, Epi epi) {
    __shared__ alignas(16) u16 As[128 * 32];
    __shared__ alignas(16) u16 Bs[128 * 32];
    int n0 = blockIdx.x * 128, m0 = blockIdx.y * 128;
    int tid = threadIdx.x, wave = tid >> 6, lane = tid & 63;
    int wm = wave >> 1, wn = wave & 1;
    int lrow = lane & 15, lquad = lane >> 4;
    int grow = tid >> 2, gcol = (tid & 3) * 8;
    const u16* Ab = A + (long)m0 * lda;
    const u16* Bb = B + (long)n0 * ldb;
    f32x4 acc[4][4] = {};
    for (int k0 = 0; k0 < K; k0 += 32) {
        gload_lds16(Ab + (long)grow * lda + k0 + gcol,        As + grow * 32 + gcol);
        gload_lds16(Ab + (long)(grow + 64) * lda + k0 + gcol, As + (grow + 64) * 32 + gcol);
        gload_lds16(Bb + (long)grow * ldb + k0 + gcol,        Bs + grow * 32 + gcol);
        gload_lds16(Bb + (long)(grow + 64) * ldb + k0 + gcol, Bs + (grow + 64) * 32 + gcol);
        __syncthreads();
        bf16x8 af[4], bfr[4];
        #pragma unroll
        for (int mt = 0; mt < 4; ++mt)
            af[mt] = *(const bf16x8*)(As + (wm * 64 + mt * 16 + lrow) * 32 + lquad * 8);
        #pragma unroll
        for (int nt = 0; nt < 4; ++nt)
            bfr[nt] = *(const bf16x8*)(Bs + (wn * 64 + nt * 16 + lrow) * 32 + lquad * 8);
        #pragma unroll
        for (int mt = 0; mt < 4; ++mt)
            #pragma unroll
            for (int nt = 0; nt < 4; ++nt)
                acc[mt][nt] = __builtin_amdgcn_mfma_f32_16x16x32_bf16(af[mt], bfr[nt], acc[mt][nt], 0, 0, 0);
        __syncthreads();
    }
    #pragma unroll
    for (int mt = 0; mt < 4; ++mt)
        #pragma unroll
        for (int nt = 0; nt < 4; ++nt) {
            int rowp = m0 + wm * 64 + mt * 16 + lquad * 4;
            int colp = n0 + wn * 64 + nt * 16 + lrow;
            epi(rowp, colp, acc[mt][nt]);
        }
}

// ---------------- fused attention: 32 query rows per block ----------------
// grid 1024: id&127 = bh (XCD locality), it = id>>7; i0 = it*32.
// 4 waves j-split (128 j each); K/V fragments reused by 2 i-groups.
__global__ __launch_bounds__(256, 2) void attn_kernel(const u16* __restrict__ Qs,
                                                      const u16* __restrict__ Kt,
                                                      const u16* __restrict__ VT,
                                                      const u16* __restrict__ QR,
                                                      const float* __restrict__ uvec,
                                                      u16* __restrict__ attnOut) {
    constexpr int SLDB = 520;   // u16 stride, 1040 B (16B mult)
    constexpr int QLD = 328;    // u16 stride, 656 B (16B mult)
    __shared__ alignas(16) u16 Sb[32 * SLDB];
    __shared__ alignas(16) u16 QRs[32 * QLD];
    __shared__ float red[2][4][32];
    int id = blockIdx.x;
    int bh = id & 127, it = id >> 7;
    int b = bh >> 4, h = bh & 15;
    int i0 = it * 32;
    int tid = threadIdx.x, wave = tid >> 6, lane = tid & 63;
    int lrow = lane & 15, lquad = lane >> 4;

    // ---- stage QR slice (32 rows x 320 u16) into LDS ----
    const u16* qrg = QR + ((long)h * 2048 + b * 256 + i0) * 320;
    #pragma unroll
    for (int kk = 0; kk < 5; ++kk) {
        int idx = tid + kk * 256;          // < 1280
        int row = idx / 40, c = idx - row * 40;
        *(bf16x8*)(QRs + row * QLD + c * 8) = *(const bf16x8*)(qrg + row * 320 + c * 8);
    }

    // ---- Q fragments for two 16-row groups + u fold (Q pre-scaled 0.125) ----
    bf16x8 aq[2][2];
    #pragma unroll
    for (int iu = 0; iu < 2; ++iu) {
        const u16* qbase = Qs + (long)((h * 8 + b) * 256 + i0 + iu * 16 + lrow) * 64;
        aq[iu][0] = *(const bf16x8*)(qbase + lquad * 8);
        aq[iu][1] = *(const bf16x8*)(qbase + 32 + lquad * 8);
        #pragma unroll
        for (int j = 0; j < 8; ++j) {
            aq[iu][0][j] = (short)f2b(b2f((u16)aq[iu][0][j]) + 0.125f * uvec[lquad * 8 + j]);
            aq[iu][1][j] = (short)f2b(b2f((u16)aq[iu][1][j]) + 0.125f * uvec[32 + lquad * 8 + j]);
        }
    }

    // ---- QK^T: K frags preloaded 4 j-tiles at a time, shared by both i-groups ----
    const u16* kbase = Kt + (long)(bh * 512) * 64;
    f32x4 acc[2][8];
    #pragma unroll
    for (int half = 0; half < 2; ++half) {
        bf16x8 bk0[4], bk1[4];
        #pragma unroll
        for (int t = 0; t < 4; ++t) {
            const u16* kp = kbase + (long)(wave * 128 + (half * 4 + t) * 16 + lrow) * 64;
            bk0[t] = *(const bf16x8*)(kp + lquad * 8);
            bk1[t] = *(const bf16x8*)(kp + 32 + lquad * 8);
        }
        #pragma unroll
        for (int t = 0; t < 4; ++t)
            #pragma unroll
            for (int iu = 0; iu < 2; ++iu) {
                f32x4 a = {0.f, 0.f, 0.f, 0.f};
                a = __builtin_amdgcn_mfma_f32_16x16x32_bf16(aq[iu][0], bk0[t], a, 0, 0, 0);
                a = __builtin_amdgcn_mfma_f32_16x16x32_bf16(aq[iu][1], bk1[t], a, 0, 0, 0);
                acc[iu][half * 4 + t] = a;
            }
    }
    __syncthreads();   // QRs staged

    // ---- combine rel-term (LDS), mask; row max ----
    float m4[2][4];
    #pragma unroll
    for (int iu = 0; iu < 2; ++iu)
        #pragma unroll
        for (int r = 0; r < 4; ++r) m4[iu][r] = -1e30f;
    #pragma unroll
    for (int jt = 0; jt < 8; ++jt) {
        int j = wave * 128 + jt * 16 + lrow;
        #pragma unroll
        for (int iu = 0; iu < 2; ++iu)
            #pragma unroll
            for (int r = 0; r < 4; ++r) {
                int rloc = iu * 16 + lquad * 4 + r;
                int i = i0 + rloc;
                int s = (j - i - 256) & 1023;
                int sc = (s >= 768) ? (s - 768) : 256;
                bool ok = (j >= 256) ? ((j - 256) <= i) : (j >= i);
                float val = ok ? acc[iu][jt][r] + b2f(QRs[rloc * QLD + sc]) : -1e30f;
                acc[iu][jt][r] = val;
                m4[iu][r] = fmaxf(m4[iu][r], val);
            }
    }
    #pragma unroll
    for (int iu = 0; iu < 2; ++iu)
        #pragma unroll
        for (int r = 0; r < 4; ++r) {
            #pragma unroll
            for (int off = 1; off < 16; off <<= 1)
                m4[iu][r] = fmaxf(m4[iu][r], __shfl_xor(m4[iu][r], off));
            if (lrow == 0) red[0][wave][iu * 16 + lquad * 4 + r] = m4[iu][r];
        }
    __syncthreads();

    float gmax[2][4];
    #pragma unroll
    for (int iu = 0; iu < 2; ++iu)
        #pragma unroll
        for (int r = 0; r < 4; ++r) {
            int row = iu * 16 + lquad * 4 + r;
            gmax[iu][r] = fmaxf(fmaxf(red[0][0][row], red[0][1][row]),
                                fmaxf(red[0][2][row], red[0][3][row]));
        }

    // ---- exp, write bf16 probs, row sums ----
    float s4[2][4] = {};
    #pragma unroll
    for (int jt = 0; jt < 8; ++jt) {
        int j = wave * 128 + jt * 16 + lrow;
        #pragma unroll
        for (int iu = 0; iu < 2; ++iu)
            #pragma unroll
            for (int r = 0; r < 4; ++r) {
                float p = __expf(acc[iu][jt][r] - gmax[iu][r]);
                s4[iu][r] += p;
                Sb[(iu * 16 + lquad * 4 + r) * SLDB + j] = f2b(p);
            }
    }
    #pragma unroll
    for (int iu = 0; iu < 2; ++iu)
        #pragma unroll
        for (int r = 0; r < 4; ++r) {
            #pragma unroll
            for (int off = 1; off < 16; off <<= 1)
                s4[iu][r] += __shfl_xor(s4[iu][r], off);
            if (lrow == 0) red[1][wave][iu * 16 + lquad * 4 + r] = s4[iu][r];
        }
    __syncthreads();

    // ---- PV: wave w computes d in [w*16, w*16+16); V frags shared by 2 i-groups ----
    const u16* vbase = VT + (long)(bh * 64 + wave * 16 + lrow) * 512;
    f32x4 oacc[2] = {};
    #pragma unroll
    for (int half = 0; half < 2; ++half) {
        bf16x8 vp[8];
        #pragma unroll
        for (int t = 0; t < 8; ++t)
            vp[t] = *(const bf16x8*)(vbase + (half * 8 + t) * 32 + lquad * 8);
        #pragma unroll
        for (int t = 0; t < 8; ++t)
            #pragma unroll
            for (int iu = 0; iu < 2; ++iu) {
                bf16x8 ap = *(const bf16x8*)(Sb + (iu * 16 + lrow) * SLDB + (half * 8 + t) * 32 + lquad * 8);
                oacc[iu] = __builtin_amdgcn_mfma_f32_16x16x32_bf16(ap, vp[t], oacc[iu], 0, 0, 0);
            }
    }
    #pragma unroll
    for (int iu = 0; iu < 2; ++iu)
        #pragma unroll
        for (int r = 0; r < 4; ++r) {
            int row = iu * 16 + lquad * 4 + r;
            float inv = 1.0f / (red[1][0][row] + red[1][1][row] + red[1][2][row] + red[1][3][row]);
            attnOut[(long)(b * 256 + i0 + row) * 1024 + h * 64 + wave * 16 + lrow] = f2b(oacc[iu][r] * inv);
        }
}

// ---------------- launch ----------------

extern "C" void kernel_launch(void* const* d_in, const int* in_sizes, int n_in,
                              void* d_out, int out_size, void* d_ws, size_t ws_size,
                              hipStream_t stream) {
    (void)in_sizes; (void)n_in; (void)out_size; (void)ws_size;
    const float* x    = (const float*)d_in[0];
    const float* h    = (const float*)d_in[1];
    const float* Wqkv = (const float*)d_in[2];
    const float* Wkr  = (const float*)d_in[3];
    const float* R    = (const float*)d_in[4];
    const float* u    = (const float*)d_in[5];
    const float* v    = (const float*)d_in[6];
    const float* Wout = (const float*)d_in[7];
    float* out = (float*)d_out;

    char* ws = (char*)d_ws;
    size_t off = 0;
    auto alloc = [&](size_t bytes) -> void* {
        void* p = ws + off;
        off = (off + bytes + 255) & ~(size_t)255;
        return p;
    };
    u16* catBF  = (u16*)alloc(4096L * 1024 * 2);   // [b*512][1024]
    u16* WqkvT  = (u16*)alloc(3072L * 1024 * 2);
    u16* WkrT   = (u16*)alloc(1024L * 1024 * 2);
    u16* WoutT  = (u16*)alloc(1024L * 1024 * 2);
    u16* RWg    = (u16*)alloc(320L * 1024 * 2);    // live shift rows of R@Wkr
    u16* Q      = (u16*)alloc(16L * 8 * 256 * 64 * 2);   // [h][b][i][d], 0.125*q
    u16* Kt     = (u16*)alloc(8L * 16 * 512 * 64 * 2);   // [b][h][t][d]
    u16* Vtmp   = (u16*)alloc(8L * 16 * 512 * 64 * 2);   // [b][h][t][d]
    u16* VT     = (u16*)alloc(8L * 16 * 64 * 512 * 2);   // [b][h][d][t]
    u16* QR     = (u16*)alloc(16L * 2048 * 320 * 2);     // [h][b*256+i][sc]
    u16* attnO  = (u16*)alloc(2048L * 1024 * 2);   // [b*256+i][h*64+d]

    cast_cat<<<2048, 256, 0, stream>>>(x, h, catBF);
    transpose_cast3<<<dim3(96, 32, 3), 256, 0, stream>>>(Wqkv, WqkvT, Wkr, WkrT, Wout, WoutT);

    // RWg = (live rows of R) @ Wkr  (M=320, K=1024), f32 A + row remap
    gemm_bt<EpiStoreBf, true, false, true><<<dim3(16, 5, 1), 256, 0, stream>>>(
        (const void*)R, 1024, 0L, WkrT, 1024, 0L, 1024, EpiStoreBf{RWg, 1024, 0}, nullptr);
    // QKV^T = Wqkv^T-rows as A (3072), cat as B (4096) -> vectorized ushort4 epilogue
    gemm128t<<<dim3(32, 24), 256, 0, stream>>>(WqkvT, 1024, catBF, 1024, 1024,
                                               EpiQKV4{Q, Kt, Vtmp});
    transpose_v<<<dim3(16, 2, 128), 256, 0, stream>>>(Vtmp, VT);
    // QR[h] = (0.125*(q+v))[h] @ RWg[:, h*64:+64]^T  (M=2048, N=320, K=64)
    gemm_bt<EpiStoreBf, false, true><<<dim3(5, 32, 16), 256, 0, stream>>>(
        (const void*)Q, 64, 2048L * 64, RWg, 1024, 64L, 64,
        EpiStoreBf{QR, 320, 2048L * 320}, v);
    attn_kernel<<<1024, 256, 0, stream>>>(Q, Kt, VT, QR, u, attnO);
    // out = attnOut @ Wout  (2048x1024x1024)
    gemm_bt<EpiStoreF32><<<dim3(16, 32, 1), 256, 0, stream>>>(
        (const void*)attnO, 1024, 0L, WoutT, 1024, 0L, 1024, EpiStoreF32{out, 1024}, nullptr);
}

// Round 8
// 210.626 us; speedup vs baseline: 1.3873x; 1.0965x over previous
//
#include <hip/hip_runtime.h>
#include <hip/hip_bf16.h>
#include <math.h>

typedef unsigned short u16;
typedef short bf16x8 __attribute__((ext_vector_type(8)));
typedef float f32x4 __attribute__((ext_vector_type(4)));

__device__ __forceinline__ u16 f2b(float f) {
    __hip_bfloat16 h = __float2bfloat16(f);
    return *reinterpret_cast<u16*>(&h);
}
__device__ __forceinline__ float b2f(u16 v) {
    __hip_bfloat16 h;
    *reinterpret_cast<u16*>(&h) = v;
    return __bfloat162float(h);
}

__device__ __forceinline__ void gload_lds16(const void* g, void* l) {
    __builtin_amdgcn_global_load_lds(
        (const __attribute__((address_space(1))) void*)g,
        (__attribute__((address_space(3))) void*)l, 16, 0, 0);
}

// ---------------- epilogues ----------------

// Tile epilogue for transposed QKV GEMM: rowp = weight-col base (4 consecutive
// values in vals), colp = pos index. All stores ushort4, coalesced.
struct EpiQKV4 {
    u16 *Q, *Kt, *Vt;
    __device__ void operator()(int rowp, int colp, f32x4 vals) const {
        int b = colp >> 9, pos = colp & 511;
        int sec = rowp >> 10, cc = rowp & 1023;
        int head = cc >> 6, d0 = cc & 63;
        ushort4 o;
        if (sec == 0) {
            if (pos < 256) return;
            o.x = f2b(vals[0] * 0.125f); o.y = f2b(vals[1] * 0.125f);
            o.z = f2b(vals[2] * 0.125f); o.w = f2b(vals[3] * 0.125f);
            *(ushort4*)(Q + (long)((head * 8 + b) * 256 + (pos - 256)) * 64 + d0) = o;
        } else {
            u16* dst = (sec == 1) ? Kt : Vt;
            o.x = f2b(vals[0]); o.y = f2b(vals[1]);
            o.z = f2b(vals[2]); o.w = f2b(vals[3]);
            *(ushort4*)(dst + (long)((b * 16 + head) * 512 + pos) * 64 + d0) = o;
        }
    }
};

struct EpiStoreBf {
    u16* C; long ldc; long strideZ;
    __device__ void operator()(int z, int row, int col, float val) const {
        C[(long)z * strideZ + (long)row * ldc + col] = f2b(val);
    }
};

struct EpiStoreF32 {
    float* C; long ldc;
    __device__ void operator()(int z, int row, int col, float val) const {
        C[(long)row * ldc + col] = val;
    }
};

// ---------------- 64x64-tile GEMM body (C = A @ B^T), LDS-staged ----------------
// Requires 14336 bytes of smem (2 x 64 x 56 x 2B).
// AF32: A is f32, converted during staging. ADDA: add 0.125*av[k] to A frags.
// ROWMAP: A row remap r -> (r<256 ? 768+r : 0).

template <typename Epi, bool AF32, bool ADDA, bool ROWMAP>
__device__ __forceinline__ void gemm_bt_body(char* smem, int bx, int by, int bz,
                                             const void* __restrict__ Av, int lda, long strideAz,
                                             const u16* __restrict__ B, int ldb, long strideBz,
                                             int K, Epi epi, const float* __restrict__ av) {
    constexpr int LDT = 56;
    u16* As = (u16*)smem;
    u16* Bs = As + 64 * LDT;
    int n0 = bx * 64, m0 = by * 64, z = bz;
    const u16* Bb = B + (long)z * strideBz + (long)n0 * ldb;
    int tid = threadIdx.x;
    int wave = tid >> 6, lane = tid & 63;
    int wm = wave >> 1, wn = wave & 1;
    int lrow = lane & 15, lquad = lane >> 4;
    int srow = tid >> 2, scol = (tid & 3) * 8;
    f32x4 acc[2][2] = {};
    for (int k0 = 0; k0 < K; k0 += 32) {
        if constexpr (AF32) {
            long arow = m0 + srow;
            if constexpr (ROWMAP) arow = (arow < 256) ? 768 + arow : 0;
            const float* src = (const float*)Av + (long)z * strideAz + arow * lda + k0 + scol;
            float4 f0 = *(const float4*)src;
            float4 f1 = *(const float4*)(src + 4);
            bf16x8 vv;
            vv[0] = (short)f2b(f0.x); vv[1] = (short)f2b(f0.y);
            vv[2] = (short)f2b(f0.z); vv[3] = (short)f2b(f0.w);
            vv[4] = (short)f2b(f1.x); vv[5] = (short)f2b(f1.y);
            vv[6] = (short)f2b(f1.z); vv[7] = (short)f2b(f1.w);
            *(bf16x8*)(As + srow * LDT + scol) = vv;
        } else {
            const u16* Ab = (const u16*)Av + (long)z * strideAz + (long)m0 * lda;
            *(bf16x8*)(As + srow * LDT + scol) = *(const bf16x8*)(Ab + (long)srow * lda + k0 + scol);
        }
        *(bf16x8*)(Bs + srow * LDT + scol) = *(const bf16x8*)(Bb + (long)srow * ldb + k0 + scol);
        __syncthreads();
        bf16x8 af[2], bfr[2];
        #pragma unroll
        for (int mt = 0; mt < 2; ++mt) {
            af[mt] = *(const bf16x8*)(As + (wm * 32 + mt * 16 + lrow) * LDT + lquad * 8);
            if constexpr (ADDA) {
                #pragma unroll
                for (int j = 0; j < 8; ++j)
                    af[mt][j] = (short)f2b(b2f((u16)af[mt][j]) + 0.125f * av[k0 + lquad * 8 + j]);
            }
        }
        #pragma unroll
        for (int nt = 0; nt < 2; ++nt)
            bfr[nt] = *(const bf16x8*)(Bs + (wn * 32 + nt * 16 + lrow) * LDT + lquad * 8);
        #pragma unroll
        for (int mt = 0; mt < 2; ++mt)
            #pragma unroll
            for (int nt = 0; nt < 2; ++nt)
                acc[mt][nt] = __builtin_amdgcn_mfma_f32_16x16x32_bf16(af[mt], bfr[nt], acc[mt][nt], 0, 0, 0);
        __syncthreads();
    }
    #pragma unroll
    for (int mt = 0; mt < 2; ++mt)
        #pragma unroll
        for (int nt = 0; nt < 2; ++nt)
            #pragma unroll
            for (int r = 0; r < 4; ++r) {
                int row = m0 + wm * 32 + mt * 16 + lquad * 4 + r;
                int col = n0 + wn * 32 + nt * 16 + lrow;
                epi(z, row, col, acc[mt][nt][r]);
            }
}

// ---------------- prep: cast_cat + all three weight transposes ----------------
// grid: [0,2048) cast_cat; [2048,5120) Wqkv; [5120,6144) Wkr; [6144,7168) Wout.
__global__ __launch_bounds__(256) void prep_kernel(const float* __restrict__ x,
                                                   const float* __restrict__ h,
                                                   u16* __restrict__ catBF,
                                                   const float* __restrict__ Wqkv, u16* __restrict__ WqkvT,
                                                   const float* __restrict__ Wkr,  u16* __restrict__ WkrT,
                                                   const float* __restrict__ Wout, u16* __restrict__ WoutT) {
    __shared__ float tile[32][33];
    int bid = blockIdx.x, tid = threadIdx.x;
    if (bid < 2048) {
        int idx = (bid * 256 + tid) * 8;
        int c = idx & 1023, r = idx >> 10;
        int b = r >> 9, pos = r & 511;
        const float* src = (pos < 256) ? h + ((long)(b * 256 + pos) * 1024 + c)
                                       : x + ((long)(b * 256 + pos - 256) * 1024 + c);
        float4 f0 = *(const float4*)src;
        float4 f1 = *(const float4*)(src + 4);
        bf16x8 vv;
        vv[0] = (short)f2b(f0.x); vv[1] = (short)f2b(f0.y);
        vv[2] = (short)f2b(f0.z); vv[3] = (short)f2b(f0.w);
        vv[4] = (short)f2b(f1.x); vv[5] = (short)f2b(f1.y);
        vv[6] = (short)f2b(f1.z); vv[7] = (short)f2b(f1.w);
        *(bf16x8*)(catBF + idx) = vv;
        return;
    }
    const float* W; u16* WT; int nb, kb;
    if (bid < 5120) {
        int w = bid - 2048;  // 96 x 32 tiles
        W = Wqkv; WT = WqkvT;
        nb = (w % 96) * 32; kb = (w / 96) * 32;
        int tx = tid & 31, ty = tid >> 5;
        #pragma unroll
        for (int i = 0; i < 32; i += 8)
            tile[ty + i][tx] = W[(long)(kb + ty + i) * 3072 + nb + tx];
    } else {
        int w = bid - 5120;
        if (w < 1024) { W = Wkr; WT = WkrT; }
        else          { W = Wout; WT = WoutT; w -= 1024; }
        nb = (w & 31) * 32; kb = (w >> 5) * 32;
        int tx = tid & 31, ty = tid >> 5;
        #pragma unroll
        for (int i = 0; i < 32; i += 8)
            tile[ty + i][tx] = W[(long)(kb + ty + i) * 1024 + nb + tx];
    }
    __syncthreads();
    int row = tid >> 3;
    int c4 = (tid & 7) * 4;
    ushort4 o;
    o.x = f2b(tile[c4 + 0][row]);
    o.y = f2b(tile[c4 + 1][row]);
    o.z = f2b(tile[c4 + 2][row]);
    o.w = f2b(tile[c4 + 3][row]);
    *(ushort4*)(WT + (long)(nb + row) * 1024 + kb + c4) = o;
}

// ---------------- QKV GEMM (BK=64, two [128][32] panels) + RWg GEMM ----------------
// bid < 768: QKV^T tile (A=WqkvT 3072 rows, B=catBF 4096 rows).
// bid >= 768: RWg = (live R rows) @ WkrT, 80 blocks of 64x64.
__global__ __launch_bounds__(256) void qkv_rwg_kernel(const u16* __restrict__ A, const u16* __restrict__ B,
                                                      EpiQKV4 eq,
                                                      const float* __restrict__ R, const u16* __restrict__ WkrT,
                                                      u16* __restrict__ RWg) {
    __shared__ alignas(16) char smem[32768];
    int bid = blockIdx.x;
    if (bid >= 768) {
        int bid2 = bid - 768;
        gemm_bt_body<EpiStoreBf, true, false, true>(smem, bid2 & 15, bid2 >> 4, 0,
            (const void*)R, 1024, 0L, WkrT, 1024, 0L, 1024, EpiStoreBf{RWg, 1024, 0}, nullptr);
        return;
    }
    int n0 = (bid & 31) * 128, m0 = (bid >> 5) * 128;
    u16* As = (u16*)smem;          // 4 panels [64][32] each per operand
    u16* Bs = As + 8192;
    int tid = threadIdx.x, wave = tid >> 6, lane = tid & 63;
    int wm = wave >> 1, wn = wave & 1;
    int lrow = lane & 15, lquad = lane >> 4;
    const u16* Ab = A + (long)m0 * 1024;
    const u16* Bb = B + (long)n0 * 1024;
    f32x4 acc[4][4] = {};
    for (int k0 = 0; k0 < 1024; k0 += 64) {
        #pragma unroll
        for (int i = 0; i < 4; ++i) {
            int rowb = (i & 1) * 64 + (tid >> 2);
            int col = k0 + (i >> 1) * 32 + (tid & 3) * 8;
            gload_lds16(Ab + (long)rowb * 1024 + col, As + i * 2048 + tid * 8);
            gload_lds16(Bb + (long)rowb * 1024 + col, Bs + i * 2048 + tid * 8);
        }
        __syncthreads();
        #pragma unroll
        for (int ks = 0; ks < 2; ++ks) {
            bf16x8 af[4], bfr[4];
            #pragma unroll
            for (int mt = 0; mt < 4; ++mt)
                af[mt] = *(const bf16x8*)(As + ks * 4096 + (wm * 64 + mt * 16 + lrow) * 32 + lquad * 8);
            #pragma unroll
            for (int nt = 0; nt < 4; ++nt)
                bfr[nt] = *(const bf16x8*)(Bs + ks * 4096 + (wn * 64 + nt * 16 + lrow) * 32 + lquad * 8);
            #pragma unroll
            for (int mt = 0; mt < 4; ++mt)
                #pragma unroll
                for (int nt = 0; nt < 4; ++nt)
                    acc[mt][nt] = __builtin_amdgcn_mfma_f32_16x16x32_bf16(af[mt], bfr[nt], acc[mt][nt], 0, 0, 0);
        }
        __syncthreads();
    }
    #pragma unroll
    for (int mt = 0; mt < 4; ++mt)
        #pragma unroll
        for (int nt = 0; nt < 4; ++nt) {
            int rowp = m0 + wm * 64 + mt * 16 + lquad * 4;
            int colp = n0 + wn * 64 + nt * 16 + lrow;
            eq(rowp, colp, acc[mt][nt]);
        }
}

// ---------------- V-transpose + QR GEMM in one launch ----------------
// bid < 4096: Vtmp [bh][t][d] -> VT [bh][d][t] (32x32 tiles).
// bid >= 4096: QR[h] = (0.125*(q+v))[h] @ RWg[:, h*64:+64]^T, 2560 blocks.
__global__ __launch_bounds__(256) void vtrans_qr_kernel(const u16* __restrict__ Vtmp, u16* __restrict__ VT,
                                                        const u16* __restrict__ Q, const u16* __restrict__ RWg,
                                                        u16* __restrict__ QR, const float* __restrict__ v) {
    __shared__ alignas(16) char smem[14336];   // gemm_bt_body needs 2*64*56*2 B
    int bid = blockIdx.x, tid = threadIdx.x;
    if (bid < 4096) {
        u16 (*tile)[34] = (u16(*)[34])smem;
        int t0 = (bid & 15) * 32, d0 = ((bid >> 4) & 1) * 32, bh = bid >> 5;
        int tx = tid & 31, ty = tid >> 5;
        const u16* src = Vtmp + (long)bh * 512 * 64;
        #pragma unroll
        for (int i = 0; i < 32; i += 8)
            tile[ty + i][tx] = src[(long)(t0 + ty + i) * 64 + d0 + tx];
        __syncthreads();
        u16* dst = VT + (long)bh * 64 * 512;
        #pragma unroll
        for (int i = 0; i < 32; i += 8)
            dst[(long)(d0 + ty + i) * 512 + t0 + tx] = tile[tx][ty + i];
        return;
    }
    int bid2 = bid - 4096;
    int bx = bid2 % 5;
    int rest = bid2 / 5;
    int by = rest & 31, bz = rest >> 5;
    gemm_bt_body<EpiStoreBf, false, true, false>(smem, bx, by, bz,
        (const void*)Q, 64, 2048L * 64, RWg, 1024, 64L, 64,
        EpiStoreBf{QR, 320, 2048L * 320}, v);
}

// ---------------- out-proj ----------------
__global__ __launch_bounds__(256) void outproj_kernel(const u16* __restrict__ A,
                                                      const u16* __restrict__ B,
                                                      float* __restrict__ out) {
    __shared__ alignas(16) char smem[14336];   // gemm_bt_body needs 2*64*56*2 B
    gemm_bt_body<EpiStoreF32, false, false, false>(smem, blockIdx.x, blockIdx.y, 0,
        (const void*)A, 1024, 0L, B, 1024, 0L, 1024, EpiStoreF32{out, 1024}, nullptr);
}

// ---------------- fused attention: 32 query rows per block ----------------
__global__ __launch_bounds__(256, 2) void attn_kernel(const u16* __restrict__ Qs,
                                                      const u16* __restrict__ Kt,
                                                      const u16* __restrict__ VT,
                                                      const u16* __restrict__ QR,
                                                      const float* __restrict__ uvec,
                                                      u16* __restrict__ attnOut) {
    constexpr int SLDB = 520;
    constexpr int QLD = 328;
    __shared__ alignas(16) u16 Sb[32 * SLDB];
    __shared__ alignas(16) u16 QRs[32 * QLD];
    __shared__ float red[2][4][32];
    int id = blockIdx.x;
    int bh = id & 127, it = id >> 7;
    int b = bh >> 4, h = bh & 15;
    int i0 = it * 32;
    int tid = threadIdx.x, wave = tid >> 6, lane = tid & 63;
    int lrow = lane & 15, lquad = lane >> 4;

    const u16* qrg = QR + ((long)h * 2048 + b * 256 + i0) * 320;
    #pragma unroll
    for (int kk = 0; kk < 5; ++kk) {
        int idx = tid + kk * 256;
        int row = idx / 40, c = idx - row * 40;
        *(bf16x8*)(QRs + row * QLD + c * 8) = *(const bf16x8*)(qrg + row * 320 + c * 8);
    }

    bf16x8 aq[2][2];
    #pragma unroll
    for (int iu = 0; iu < 2; ++iu) {
        const u16* qbase = Qs + (long)((h * 8 + b) * 256 + i0 + iu * 16 + lrow) * 64;
        aq[iu][0] = *(const bf16x8*)(qbase + lquad * 8);
        aq[iu][1] = *(const bf16x8*)(qbase + 32 + lquad * 8);
        #pragma unroll
        for (int j = 0; j < 8; ++j) {
            aq[iu][0][j] = (short)f2b(b2f((u16)aq[iu][0][j]) + 0.125f * uvec[lquad * 8 + j]);
            aq[iu][1][j] = (short)f2b(b2f((u16)aq[iu][1][j]) + 0.125f * uvec[32 + lquad * 8 + j]);
        }
    }

    const u16* kbase = Kt + (long)(bh * 512) * 64;
    f32x4 acc[2][8];
    #pragma unroll
    for (int half = 0; half < 2; ++half) {
        bf16x8 bk0[4], bk1[4];
        #pragma unroll
        for (int t = 0; t < 4; ++t) {
            const u16* kp = kbase + (long)(wave * 128 + (half * 4 + t) * 16 + lrow) * 64;
            bk0[t] = *(const bf16x8*)(kp + lquad * 8);
            bk1[t] = *(const bf16x8*)(kp + 32 + lquad * 8);
        }
        #pragma unroll
        for (int t = 0; t < 4; ++t)
            #pragma unroll
            for (int iu = 0; iu < 2; ++iu) {
                f32x4 a = {0.f, 0.f, 0.f, 0.f};
                a = __builtin_amdgcn_mfma_f32_16x16x32_bf16(aq[iu][0], bk0[t], a, 0, 0, 0);
                a = __builtin_amdgcn_mfma_f32_16x16x32_bf16(aq[iu][1], bk1[t], a, 0, 0, 0);
                acc[iu][half * 4 + t] = a;
            }
    }
    __syncthreads();

    float m4[2][4];
    #pragma unroll
    for (int iu = 0; iu < 2; ++iu)
        #pragma unroll
        for (int r = 0; r < 4; ++r) m4[iu][r] = -1e30f;
    #pragma unroll
    for (int jt = 0; jt < 8; ++jt) {
        int j = wave * 128 + jt * 16 + lrow;
        #pragma unroll
        for (int iu = 0; iu < 2; ++iu)
            #pragma unroll
            for (int r = 0; r < 4; ++r) {
                int rloc = iu * 16 + lquad * 4 + r;
                int i = i0 + rloc;
                int s = (j - i - 256) & 1023;
                int sc = (s >= 768) ? (s - 768) : 256;
                bool ok = (j >= 256) ? ((j - 256) <= i) : (j >= i);
                float val = ok ? acc[iu][jt][r] + b2f(QRs[rloc * QLD + sc]) : -1e30f;
                acc[iu][jt][r] = val;
                m4[iu][r] = fmaxf(m4[iu][r], val);
            }
    }
    #pragma unroll
    for (int iu = 0; iu < 2; ++iu)
        #pragma unroll
        for (int r = 0; r < 4; ++r) {
            #pragma unroll
            for (int off = 1; off < 16; off <<= 1)
                m4[iu][r] = fmaxf(m4[iu][r], __shfl_xor(m4[iu][r], off));
            if (lrow == 0) red[0][wave][iu * 16 + lquad * 4 + r] = m4[iu][r];
        }
    __syncthreads();

    float gmax[2][4];
    #pragma unroll
    for (int iu = 0; iu < 2; ++iu)
        #pragma unroll
        for (int r = 0; r < 4; ++r) {
            int row = iu * 16 + lquad * 4 + r;
            gmax[iu][r] = fmaxf(fmaxf(red[0][0][row], red[0][1][row]),
                                fmaxf(red[0][2][row], red[0][3][row]));
        }

    float s4[2][4] = {};
    #pragma unroll
    for (int jt = 0; jt < 8; ++jt) {
        int j = wave * 128 + jt * 16 + lrow;
        #pragma unroll
        for (int iu = 0; iu < 2; ++iu)
            #pragma unroll
            for (int r = 0; r < 4; ++r) {
                float p = __expf(acc[iu][jt][r] - gmax[iu][r]);
                s4[iu][r] += p;
                Sb[(iu * 16 + lquad * 4 + r) * SLDB + j] = f2b(p);
            }
    }
    #pragma unroll
    for (int iu = 0; iu < 2; ++iu)
        #pragma unroll
        for (int r = 0; r < 4; ++r) {
            #pragma unroll
            for (int off = 1; off < 16; off <<= 1)
                s4[iu][r] += __shfl_xor(s4[iu][r], off);
            if (lrow == 0) red[1][wave][iu * 16 + lquad * 4 + r] = s4[iu][r];
        }
    __syncthreads();

    const u16* vbase = VT + (long)(bh * 64 + wave * 16 + lrow) * 512;
    f32x4 oacc[2] = {};
    #pragma unroll
    for (int half = 0; half < 2; ++half) {
        bf16x8 vp[8];
        #pragma unroll
        for (int t = 0; t < 8; ++t)
            vp[t] = *(const bf16x8*)(vbase + (half * 8 + t) * 32 + lquad * 8);
        #pragma unroll
        for (int t = 0; t < 8; ++t)
            #pragma unroll
            for (int iu = 0; iu < 2; ++iu) {
                bf16x8 ap = *(const bf16x8*)(Sb + (iu * 16 + lrow) * SLDB + (half * 8 + t) * 32 + lquad * 8);
                oacc[iu] = __builtin_amdgcn_mfma_f32_16x16x32_bf16(ap, vp[t], oacc[iu], 0, 0, 0);
            }
    }
    #pragma unroll
    for (int iu = 0; iu < 2; ++iu)
        #pragma unroll
        for (int r = 0; r < 4; ++r) {
            int row = iu * 16 + lquad * 4 + r;
            float inv = 1.0f / (red[1][0][row] + red[1][1][row] + red[1][2][row] + red[1][3][row]);
            attnOut[(long)(b * 256 + i0 + row) * 1024 + h * 64 + wave * 16 + lrow] = f2b(oacc[iu][r] * inv);
        }
}

// ---------------- launch ----------------

extern "C" void kernel_launch(void* const* d_in, const int* in_sizes, int n_in,
                              void* d_out, int out_size, void* d_ws, size_t ws_size,
                              hipStream_t stream) {
    (void)in_sizes; (void)n_in; (void)out_size; (void)ws_size;
    const float* x    = (const float*)d_in[0];
    const float* h    = (const float*)d_in[1];
    const float* Wqkv = (const float*)d_in[2];
    const float* Wkr  = (const float*)d_in[3];
    const float* R    = (const float*)d_in[4];
    const float* u    = (const float*)d_in[5];
    const float* v    = (const float*)d_in[6];
    const float* Wout = (const float*)d_in[7];
    float* out = (float*)d_out;

    char* ws = (char*)d_ws;
    size_t off = 0;
    auto alloc = [&](size_t bytes) -> void* {
        void* p = ws + off;
        off = (off + bytes + 255) & ~(size_t)255;
        return p;
    };
    u16* catBF  = (u16*)alloc(4096L * 1024 * 2);   // [b*512][1024]
    u16* WqkvT  = (u16*)alloc(3072L * 1024 * 2);
    u16* WkrT   = (u16*)alloc(1024L * 1024 * 2);
    u16* WoutT  = (u16*)alloc(1024L * 1024 * 2);
    u16* RWg    = (u16*)alloc(320L * 1024 * 2);    // live shift rows of R@Wkr
    u16* Q      = (u16*)alloc(16L * 8 * 256 * 64 * 2);   // [h][b][i][d], 0.125*q
    u16* Kt     = (u16*)alloc(8L * 16 * 512 * 64 * 2);   // [b][h][t][d]
    u16* Vtmp   = (u16*)alloc(8L * 16 * 512 * 64 * 2);   // [b][h][t][d]
    u16* VT     = (u16*)alloc(8L * 16 * 64 * 512 * 2);   // [b][h][d][t]
    u16* QR     = (u16*)alloc(16L * 2048 * 320 * 2);     // [h][b*256+i][sc]
    u16* attnO  = (u16*)alloc(2048L * 1024 * 2);   // [b*256+i][h*64+d]

    prep_kernel<<<7168, 256, 0, stream>>>(x, h, catBF, Wqkv, WqkvT, Wkr, WkrT, Wout, WoutT);
    qkv_rwg_kernel<<<848, 256, 0, stream>>>(WqkvT, catBF, EpiQKV4{Q, Kt, Vtmp}, R, WkrT, RWg);
    vtrans_qr_kernel<<<6656, 256, 0, stream>>>(Vtmp, VT, Q, RWg, QR, v);
    attn_kernel<<<1024, 256, 0, stream>>>(Q, Kt, VT, QR, u, attnO);
    outproj_kernel<<<dim3(16, 32), 256, 0, stream>>>(attnO, WoutT, out);
}